// Round 1
// baseline (822.030 us; speedup 1.0000x reference)
//
#include <hip/hip_runtime.h>
#include <hip/hip_bf16.h>

// ---------------------------------------------------------------------------
// GAT 2-layer: gemm1 -> alpha1 -> CSR build -> agg1(online softmax, no atomics)
//              -> BN stats -> BN finalize -> BN+ELU -> gemm2 -> alpha2 -> agg2
// All fp32. CSR (by dst, with self-loops) rebuilt every call from edge_index.
// ---------------------------------------------------------------------------

#define THREADS 256

// ---------------- CSR build ----------------

__global__ void k_count(const int* __restrict__ dstv, int E, int* __restrict__ deg) {
    int e = blockIdx.x * THREADS + threadIdx.x;
    if (e < E) atomicAdd(&deg[dstv[e]], 1);
}

// one block, 1024 threads. deg_cursor holds degree in, cursor out (=rowptr+1).
// Also writes rowptr[0..N] and the self-loop entry at the start of each segment.
__global__ void k_scan(int* __restrict__ deg_cursor, int* __restrict__ rowptr,
                       int* __restrict__ colx, int Nn) {
    __shared__ int sm[1024];
    int t = threadIdx.x;
    const int CH = (Nn + 1023) >> 10;
    int b0 = t * CH, b1 = b0 + CH; if (b1 > Nn) b1 = Nn; if (b0 > Nn) b0 = Nn;
    int sum = 0;
    for (int i = b0; i < b1; ++i) sum += deg_cursor[i] + 1;   // +1 self loop
    sm[t] = sum;
    __syncthreads();
    for (int off = 1; off < 1024; off <<= 1) {
        int v = (t >= off) ? sm[t - off] : 0;
        __syncthreads();
        sm[t] += v;
        __syncthreads();
    }
    int base = sm[t] - sum;   // exclusive prefix
    for (int i = b0; i < b1; ++i) {
        int d = deg_cursor[i];
        rowptr[i] = base;
        colx[base] = i;            // self loop first in segment
        deg_cursor[i] = base + 1;  // cursor for scatter
        base += d + 1;
    }
    if (t == 1023) rowptr[Nn] = sm[1023];
}

__global__ void k_scatter(const int* __restrict__ srcv, const int* __restrict__ dstv,
                          int E, int* __restrict__ cursor, int* __restrict__ colx) {
    int e = blockIdx.x * THREADS + threadIdx.x;
    if (e >= E) return;
    int pos = atomicAdd(&cursor[dstv[e]], 1);
    colx[pos] = srcv[e];
}

// ---------------- GEMM1: h1[M,256] = A[M,256] @ B[256,256] ----------------

#define BM 128
#define BN 64
#define BK 16

__global__ __launch_bounds__(256) void k_gemm1(const float* __restrict__ A,
                                               const float* __restrict__ B,
                                               float* __restrict__ C, int M) {
    __shared__ float As[BK][BM + 4];  // +4 pad: conflict spread, keeps 16B align
    __shared__ float Bs[BK][BN + 4];
    int t = threadIdx.x;
    int tx = t & 15, ty = t >> 4;          // 16x16 threads, 4x8 micro-tile
    int row0 = blockIdx.x * BM, col0 = blockIdx.y * BN;
    float acc[8][4] = {};
    for (int k0 = 0; k0 < 256; k0 += BK) {
        #pragma unroll
        for (int p = 0; p < 2; ++p) {      // A: 128x16 = 512 float4-slots/4
            int slot = t + p * 256;        // 0..511
            int r = slot >> 2, cq = slot & 3;
            int grow = row0 + r;
            float4 v = {0.f, 0.f, 0.f, 0.f};
            if (grow < M) v = *(const float4*)&A[(size_t)grow * 256 + k0 + cq * 4];
            As[cq * 4 + 0][r] = v.x; As[cq * 4 + 1][r] = v.y;
            As[cq * 4 + 2][r] = v.z; As[cq * 4 + 3][r] = v.w;
        }
        {
            int kr = t >> 4, nc = (t & 15) * 4;   // B: 16x64
            float4 v = *(const float4*)&B[(size_t)(k0 + kr) * 256 + col0 + nc];
            *(float4*)&Bs[kr][nc] = v;
        }
        __syncthreads();
        #pragma unroll
        for (int kk = 0; kk < BK; ++kk) {
            float4 a0 = *(const float4*)&As[kk][ty * 8];
            float4 a1 = *(const float4*)&As[kk][ty * 8 + 4];
            float4 bv = *(const float4*)&Bs[kk][tx * 4];
            float a[8] = {a0.x, a0.y, a0.z, a0.w, a1.x, a1.y, a1.z, a1.w};
            float b[4] = {bv.x, bv.y, bv.z, bv.w};
            #pragma unroll
            for (int i = 0; i < 8; ++i)
                #pragma unroll
                for (int j = 0; j < 4; ++j) acc[i][j] += a[i] * b[j];
        }
        __syncthreads();
    }
    #pragma unroll
    for (int i = 0; i < 8; ++i) {
        int grow = row0 + ty * 8 + i;
        if (grow < M) {
            float4 v = {acc[i][0], acc[i][1], acc[i][2], acc[i][3]};
            *(float4*)&C[(size_t)grow * 256 + col0 + tx * 4] = v;
        }
    }
}

// ---------------- alpha1: per (node, head) dot over 32 channels ----------------

__global__ void k_alpha1(const float* __restrict__ h1, const float* __restrict__ atts,
                         const float* __restrict__ attd, float* __restrict__ as1,
                         float* __restrict__ ad1, int total) {   // total = N*8
    int t = blockIdx.x * THREADS + threadIdx.x;
    if (t >= total) return;
    int h = t & 7;
    const float4* hp = (const float4*)&h1[(size_t)(t >> 3) * 256 + h * 32];
    const float4* ap = (const float4*)&atts[h * 32];
    const float4* dp = (const float4*)&attd[h * 32];
    float s = 0.f, d = 0.f;
    #pragma unroll
    for (int j = 0; j < 8; ++j) {
        float4 v = hp[j], a = ap[j], b = dp[j];
        s += v.x * a.x + v.y * a.y + v.z * a.z + v.w * a.w;
        d += v.x * b.x + v.y * b.y + v.z * b.z + v.w * b.w;
    }
    as1[t] = s; ad1[t] = d;
}

// ---------------- agg1: wave per node, online softmax, no atomics ----------------

__global__ __launch_bounds__(256) void k_agg1(const float* __restrict__ h1,
                                              const float* __restrict__ as1,
                                              const float* __restrict__ ad1,
                                              const int* __restrict__ rowptr,
                                              const int* __restrict__ colx,
                                              const float* __restrict__ b1,
                                              float* __restrict__ hb, int Nn) {
    int lane = threadIdx.x & 63, w = threadIdx.x >> 6;
    int n = blockIdx.x * 4 + w;
    if (n >= Nn) return;
    int head = lane >> 3;                  // lane covers channels [4*lane, 4*lane+4)
    float ad = ad1[n * 8 + head];
    int beg = rowptr[n], end = rowptr[n + 1];
    float m = -1e30f, s = 0.f;
    float4 acc = {0.f, 0.f, 0.f, 0.f};
    for (int i = beg; i < end; ++i) {
        int src = colx[i];
        float e = as1[src * 8 + head] + ad;
        e = e > 0.f ? e : 0.2f * e;        // leaky relu 0.2
        float4 hv = *(const float4*)&h1[(size_t)src * 256 + lane * 4];
        float nm = fmaxf(m, e);
        float r = __expf(m - nm);
        float p = __expf(e - nm);
        s = s * r + p;
        acc.x = acc.x * r + p * hv.x;
        acc.y = acc.y * r + p * hv.y;
        acc.z = acc.z * r + p * hv.z;
        acc.w = acc.w * r + p * hv.w;
        m = nm;
    }
    float inv = 1.f / (s + 1e-16f);
    float4 bv = *(const float4*)&b1[lane * 4];
    float4 o = {acc.x * inv + bv.x, acc.y * inv + bv.y,
                acc.z * inv + bv.z, acc.w * inv + bv.w};
    *(float4*)&hb[(size_t)n * 256 + lane * 4] = o;
}

// ---------------- BatchNorm ----------------

__global__ __launch_bounds__(256) void k_bnstats(const float* __restrict__ hb,
                                                 float* __restrict__ bnsum,
                                                 float* __restrict__ bnssum, int Nn) {
    int c = threadIdx.x;
    float s = 0.f, ss = 0.f;
    for (int r = blockIdx.x; r < Nn; r += gridDim.x) {
        float v = hb[(size_t)r * 256 + c];
        s += v; ss += v * v;
    }
    atomicAdd(&bnsum[c], s);
    atomicAdd(&bnssum[c], ss);
}

__global__ void k_bnfinal(const float* __restrict__ bnsum, const float* __restrict__ bnssum,
                          const float* __restrict__ gamma, const float* __restrict__ beta,
                          float* __restrict__ scale, float* __restrict__ shift, int Nn) {
    int c = threadIdx.x;
    float mu = bnsum[c] / (float)Nn;
    float var = bnssum[c] / (float)Nn - mu * mu;
    float inv = rsqrtf(var + 1e-5f);
    float sc = gamma[c] * inv;
    scale[c] = sc;
    shift[c] = beta[c] - mu * sc;
}

__global__ void k_bnelu(float* __restrict__ hb, const float* __restrict__ scale,
                        const float* __restrict__ shift, int total4) {
    int i = blockIdx.x * THREADS + threadIdx.x;
    if (i >= total4) return;
    float4 v = ((float4*)hb)[i];
    int c4 = i & 63;
    float4 sc = ((const float4*)scale)[c4];
    float4 sh = ((const float4*)shift)[c4];
    float x0 = v.x * sc.x + sh.x, x1 = v.y * sc.y + sh.y;
    float x2 = v.z * sc.z + sh.z, x3 = v.w * sc.w + sh.w;
    v.x = x0 > 0.f ? x0 : __expf(x0) - 1.f;
    v.y = x1 > 0.f ? x1 : __expf(x1) - 1.f;
    v.z = x2 > 0.f ? x2 : __expf(x2) - 1.f;
    v.w = x3 > 0.f ? x3 : __expf(x3) - 1.f;
    ((float4*)hb)[i] = v;
}

// ---------------- GEMM2: h2[M,40] = H[M,256] @ W2[256,40] ----------------

__global__ __launch_bounds__(256) void k_gemm2(const float* __restrict__ H,
                                               const float* __restrict__ W2,
                                               float* __restrict__ h2, int Nn) {
    __shared__ float Ws[256 * 40];
    int t = threadIdx.x;
    for (int i = t; i < 2560; i += 256) ((float4*)Ws)[i] = ((const float4*)W2)[i];
    __syncthreads();
    int tx = t & 63, ty = t >> 6;
    int row = blockIdx.x * 4 + ty;
    if (row >= Nn) return;
    if (tx >= 40) return;
    float acc = 0.f;
    const float4* hp = (const float4*)&H[(size_t)row * 256];
    #pragma unroll 8
    for (int k4 = 0; k4 < 64; ++k4) {
        float4 h = hp[k4];
        int kb = k4 * 160 + tx;   // (k4*4)*40 + tx
        acc += h.x * Ws[kb] + h.y * Ws[kb + 40] + h.z * Ws[kb + 80] + h.w * Ws[kb + 120];
    }
    h2[(size_t)row * 40 + tx] = acc;
}

// ---------------- alpha2 ----------------

__global__ void k_alpha2(const float* __restrict__ h2, const float* __restrict__ atts,
                         const float* __restrict__ attd, float* __restrict__ as2,
                         float* __restrict__ ad2, int Nn) {
    int n = blockIdx.x * THREADS + threadIdx.x;
    if (n >= Nn) return;
    const float4* hp = (const float4*)&h2[(size_t)n * 40];
    float s = 0.f, d = 0.f;
    #pragma unroll
    for (int j = 0; j < 10; ++j) {
        float4 v = hp[j];
        float4 a = ((const float4*)atts)[j];
        float4 b = ((const float4*)attd)[j];
        s += v.x * a.x + v.y * a.y + v.z * a.z + v.w * a.w;
        d += v.x * b.x + v.y * b.y + v.z * b.z + v.w * b.w;
    }
    as2[n] = s; ad2[n] = d;
}

// ---------------- agg2: wave per node, C=40, 1 head ----------------

__global__ __launch_bounds__(256) void k_agg2(const float* __restrict__ h2,
                                              const float* __restrict__ as2,
                                              const float* __restrict__ ad2,
                                              const int* __restrict__ rowptr,
                                              const int* __restrict__ colx,
                                              const float* __restrict__ b2,
                                              float* __restrict__ out, int Nn) {
    int lane = threadIdx.x & 63, w = threadIdx.x >> 6;
    int n = blockIdx.x * 4 + w;
    if (n >= Nn) return;
    float ad = ad2[n];
    int beg = rowptr[n], end = rowptr[n + 1];
    int c = lane < 40 ? lane : 0;
    float m = -1e30f, s = 0.f, acc = 0.f;
    for (int i = beg; i < end; ++i) {
        int src = colx[i];
        float e = as2[src] + ad;
        e = e > 0.f ? e : 0.2f * e;
        float hv = h2[(size_t)src * 40 + c];
        float nm = fmaxf(m, e);
        float r = __expf(m - nm);
        float p = __expf(e - nm);
        s = s * r + p;
        acc = acc * r + p * hv;
        m = nm;
    }
    if (lane < 40) out[(size_t)n * 40 + lane] = acc / (s + 1e-16f) + b2[lane];
}

// ---------------- launch ----------------

static inline size_t rup(size_t x) { return (x + 255) & ~(size_t)255; }

extern "C" void kernel_launch(void* const* d_in, const int* in_sizes, int n_in,
                              void* d_out, int out_size, void* d_ws, size_t ws_size,
                              hipStream_t stream) {
    const float* x     = (const float*)d_in[0];
    const int*   ei    = (const int*)d_in[1];
    const float* W1    = (const float*)d_in[2];
    const float* atts1 = (const float*)d_in[3];
    const float* attd1 = (const float*)d_in[4];
    const float* b1    = (const float*)d_in[5];
    const float* gamma = (const float*)d_in[6];
    const float* beta  = (const float*)d_in[7];
    const float* W2    = (const float*)d_in[8];
    const float* atts2 = (const float*)d_in[9];
    const float* attd2 = (const float*)d_in[10];
    const float* b2    = (const float*)d_in[11];

    const int N = in_sizes[0] / 256;
    const int E = in_sizes[1] / 2;
    const int* srcv = ei;
    const int* dstv = ei + E;

    char* w = (char*)d_ws;
    float* h1 = (float*)w;      w += rup((size_t)N * 256 * 4);
    float* hb = (float*)w;      w += rup((size_t)N * 256 * 4);
    float* h2 = (float*)w;      w += rup((size_t)N * 40 * 4);
    float* as1 = (float*)w;     w += rup((size_t)N * 8 * 4);
    float* ad1 = (float*)w;     w += rup((size_t)N * 8 * 4);
    float* as2 = (float*)w;     w += rup((size_t)N * 4);
    float* ad2 = (float*)w;     w += rup((size_t)N * 4);
    int* rowptr = (int*)w;      w += rup((size_t)(N + 1) * 4);
    int* cursor = (int*)w;      w += rup((size_t)N * 4);
    int* colx = (int*)w;        w += rup((size_t)(E + N) * 4);
    float* bn = (float*)w;      w += rup(1024 * 4);
    float* bnsum = bn, *bnssum = bn + 256, *scale = bn + 512, *shift = bn + 768;

    // CSR build
    hipMemsetAsync(cursor, 0, (size_t)N * 4, stream);
    hipMemsetAsync(bn, 0, 512 * 4, stream);
    k_count<<<(E + THREADS - 1) / THREADS, THREADS, 0, stream>>>(dstv, E, cursor);
    k_scan<<<1, 1024, 0, stream>>>(cursor, rowptr, colx, N);
    k_scatter<<<(E + THREADS - 1) / THREADS, THREADS, 0, stream>>>(srcv, dstv, E, cursor, colx);

    // Layer 1
    dim3 g1((N + BM - 1) / BM, 256 / BN);
    k_gemm1<<<g1, 256, 0, stream>>>(x, W1, h1, N);
    k_alpha1<<<(N * 8 + THREADS - 1) / THREADS, THREADS, 0, stream>>>(h1, atts1, attd1, as1, ad1, N * 8);
    k_agg1<<<(N + 3) / 4, 256, 0, stream>>>(h1, as1, ad1, rowptr, colx, b1, hb, N);

    // BatchNorm + ELU
    k_bnstats<<<1024, 256, 0, stream>>>(hb, bnsum, bnssum, N);
    k_bnfinal<<<1, 256, 0, stream>>>(bnsum, bnssum, gamma, beta, scale, shift, N);
    k_bnelu<<<(N * 64 + THREADS - 1) / THREADS, THREADS, 0, stream>>>(hb, scale, shift, N * 64);

    // Layer 2
    k_gemm2<<<(N + 3) / 4, 256, 0, stream>>>(hb, W2, h2, N);
    k_alpha2<<<(N + THREADS - 1) / THREADS, THREADS, 0, stream>>>(h2, atts2, attd2, as2, ad2, N);
    k_agg2<<<(N + 3) / 4, 256, 0, stream>>>(h2, as2, ad2, rowptr, colx, b2, (float*)d_out, N);
}

// Round 3
// 571.904 us; speedup vs baseline: 1.4374x; 1.4374x over previous
//
#include <hip/hip_runtime.h>
#include <hip/hip_bf16.h>

#define THREADS 256

typedef __attribute__((ext_vector_type(8))) short short8;
typedef __attribute__((ext_vector_type(4))) float f32x4;

__device__ inline unsigned short f2bf_rn(float f) {
    unsigned u = __float_as_uint(f);
    unsigned r = (u + 0x7FFF + ((u >> 16) & 1)) >> 16;
    return (unsigned short)r;
}
__device__ inline float bf2f(unsigned short s) {
    return __uint_as_float(((unsigned)s) << 16);
}
__device__ inline void bfsplit(float f, short* hi, short* lo) {
    unsigned short h = f2bf_rn(f);
    *hi = (short)h;
    *lo = (short)f2bf_rn(f - bf2f(h));
}

// ---------------- CSR build ----------------

__global__ void k_count(const int* __restrict__ dstv, int E, int* __restrict__ deg) {
    int e = blockIdx.x * THREADS + threadIdx.x;
    if (e < E) atomicAdd(&deg[dstv[e]], 1);
}

__global__ void k_scanA(const int* __restrict__ deg, int* __restrict__ partial, int Nn) {
    __shared__ int sm[256];
    int i = blockIdx.x * 256 + threadIdx.x;
    sm[threadIdx.x] = (i < Nn) ? deg[i] + 1 : 0;
    __syncthreads();
    for (int off = 128; off > 0; off >>= 1) {
        if (threadIdx.x < off) sm[threadIdx.x] += sm[threadIdx.x + off];
        __syncthreads();
    }
    if (threadIdx.x == 0) partial[blockIdx.x] = sm[0];
}

__global__ void k_scanB(const int* __restrict__ partial, int* __restrict__ partoff,
                        int* __restrict__ rowptr, int nb, int Nn) {
    __shared__ int sm[256];
    int t = threadIdx.x;
    int v = (t < nb) ? partial[t] : 0;
    sm[t] = v;
    __syncthreads();
    for (int off = 1; off < 256; off <<= 1) {
        int u = (t >= off) ? sm[t - off] : 0;
        __syncthreads();
        sm[t] += u;
        __syncthreads();
    }
    if (t < nb) partoff[t] = sm[t] - v;
    if (t == 255) rowptr[Nn] = sm[255];
}

__global__ void k_scanC(int* __restrict__ deg_cursor, const int* __restrict__ partoff,
                        int* __restrict__ rowptr, int* __restrict__ colx, int Nn) {
    __shared__ int sm[256];
    int t = threadIdx.x;
    int i = blockIdx.x * 256 + t;
    int d = (i < Nn) ? deg_cursor[i] : 0;
    int v = (i < Nn) ? d + 1 : 0;
    sm[t] = v;
    __syncthreads();
    for (int off = 1; off < 256; off <<= 1) {
        int u = (t >= off) ? sm[t - off] : 0;
        __syncthreads();
        sm[t] += u;
        __syncthreads();
    }
    int excl = sm[t] - v + partoff[blockIdx.x];
    if (i < Nn) {
        rowptr[i] = excl;
        colx[excl] = i;             // self loop first in segment
        deg_cursor[i] = excl + 1;   // scatter cursor
    }
}

__global__ void k_scatter(const int* __restrict__ srcv, const int* __restrict__ dstv,
                          int E, int* __restrict__ cursor, int* __restrict__ colx) {
    int e = blockIdx.x * THREADS + threadIdx.x;
    if (e >= E) return;
    int pos = atomicAdd(&cursor[dstv[e]], 1);
    colx[pos] = srcv[e];
}

// ---------------- GEMM1 (MFMA split-bf16) + fused alpha1 ----------------
// h1[M,256] = x[M,256] @ W1[256,256]; as1/ad1[n,h] = sum_c h1[n,h*32+c]*att[h][c]
// Block: 128 rows x 64 cols, 4 waves (2x2), wave tile 64x32. BK=32.

__global__ __launch_bounds__(256) void k_gemm1(const float* __restrict__ A,
                                               const float* __restrict__ B,
                                               const float* __restrict__ attS,
                                               const float* __restrict__ attD,
                                               float* __restrict__ C,
                                               float* __restrict__ as1,
                                               float* __restrict__ ad1, int M) {
    __shared__ short Ash[128][40];
    __shared__ short Asl[128][40];
    __shared__ short Bsh[64][40];
    __shared__ short Bsl[64][40];
    int t = threadIdx.x;
    int l = t & 63, w = t >> 6;
    int wr = w >> 1, wc = w & 1;
    int row0 = blockIdx.x * 128, col0 = blockIdx.y * 64;
    int l16 = l & 15, lg = l >> 4;

    f32x4 zero = {0.f, 0.f, 0.f, 0.f};
    f32x4 acc[4][2];
    #pragma unroll
    for (int i = 0; i < 4; ++i) { acc[i][0] = zero; acc[i][1] = zero; }

    for (int k0 = 0; k0 < 256; k0 += 32) {
        // stage A: 128x32 fp32 -> hi/lo bf16
        #pragma unroll
        for (int p = 0; p < 4; ++p) {
            int s = t + p * 256;          // 0..1023
            int r = s >> 3, c4 = s & 7;   // row, float4 within 32 k
            int grow = row0 + r;
            float4 v = {0.f, 0.f, 0.f, 0.f};
            if (grow < M) v = *(const float4*)&A[(size_t)grow * 256 + k0 + c4 * 4];
            short h0, l0, h1, l1, h2, l2, h3, l3;
            bfsplit(v.x, &h0, &l0); bfsplit(v.y, &h1, &l1);
            bfsplit(v.z, &h2, &l2); bfsplit(v.w, &h3, &l3);
            Ash[r][c4 * 4 + 0] = h0; Ash[r][c4 * 4 + 1] = h1;
            Ash[r][c4 * 4 + 2] = h2; Ash[r][c4 * 4 + 3] = h3;
            Asl[r][c4 * 4 + 0] = l0; Asl[r][c4 * 4 + 1] = l1;
            Asl[r][c4 * 4 + 2] = l2; Asl[r][c4 * 4 + 3] = l3;
        }
        // stage B (transposed to [col][k]): 32x64
        #pragma unroll
        for (int p = 0; p < 2; ++p) {
            int s = t + p * 256;          // 0..511
            int kk = s >> 4, c4 = s & 15;
            float4 v = *(const float4*)&B[(size_t)(k0 + kk) * 256 + col0 + c4 * 4];
            short h, lo2;
            bfsplit(v.x, &h, &lo2); Bsh[c4 * 4 + 0][kk] = h; Bsl[c4 * 4 + 0][kk] = lo2;
            bfsplit(v.y, &h, &lo2); Bsh[c4 * 4 + 1][kk] = h; Bsl[c4 * 4 + 1][kk] = lo2;
            bfsplit(v.z, &h, &lo2); Bsh[c4 * 4 + 2][kk] = h; Bsl[c4 * 4 + 2][kk] = lo2;
            bfsplit(v.w, &h, &lo2); Bsh[c4 * 4 + 3][kk] = h; Bsl[c4 * 4 + 3][kk] = lo2;
        }
        __syncthreads();
        short8 ah[4], al[4], bh[2], bl[2];
        #pragma unroll
        for (int mf = 0; mf < 4; ++mf) {
            ah[mf] = *(const short8*)&Ash[wr * 64 + mf * 16 + l16][lg * 8];
            al[mf] = *(const short8*)&Asl[wr * 64 + mf * 16 + l16][lg * 8];
        }
        #pragma unroll
        for (int nf = 0; nf < 2; ++nf) {
            bh[nf] = *(const short8*)&Bsh[wc * 32 + nf * 16 + l16][lg * 8];
            bl[nf] = *(const short8*)&Bsl[wc * 32 + nf * 16 + l16][lg * 8];
        }
        #pragma unroll
        for (int mf = 0; mf < 4; ++mf)
            #pragma unroll
            for (int nf = 0; nf < 2; ++nf) {
                acc[mf][nf] = __builtin_amdgcn_mfma_f32_16x16x32_bf16(ah[mf], bh[nf], acc[mf][nf], 0, 0, 0);
                acc[mf][nf] = __builtin_amdgcn_mfma_f32_16x16x32_bf16(ah[mf], bl[nf], acc[mf][nf], 0, 0, 0);
                acc[mf][nf] = __builtin_amdgcn_mfma_f32_16x16x32_bf16(al[mf], bh[nf], acc[mf][nf], 0, 0, 0);
            }
        __syncthreads();
    }

    // C write: row = 4*lg + j (+ mf*16 + wr*64), col = l16 (+ nf*16 + wc*32)
    #pragma unroll
    for (int mf = 0; mf < 4; ++mf)
        #pragma unroll
        for (int nf = 0; nf < 2; ++nf)
            #pragma unroll
            for (int j = 0; j < 4; ++j) {
                int row = row0 + wr * 64 + mf * 16 + 4 * lg + j;
                if (row < M)
                    C[(size_t)row * 256 + col0 + wc * 32 + nf * 16 + l16] = acc[mf][nf][j];
            }

    // fused alpha: this wave covers head = blockIdx.y*2 + wc fully (32 cols)
    int hidx = blockIdx.y * 2 + wc;
    float aS0 = attS[hidx * 32 + l16],      aD0 = attD[hidx * 32 + l16];
    float aS1 = attS[hidx * 32 + 16 + l16], aD1 = attD[hidx * 32 + 16 + l16];
    #pragma unroll
    for (int mf = 0; mf < 4; ++mf) {
        float ps[4], pd[4];
        #pragma unroll
        for (int j = 0; j < 4; ++j) {
            ps[j] = acc[mf][0][j] * aS0 + acc[mf][1][j] * aS1;
            pd[j] = acc[mf][0][j] * aD0 + acc[mf][1][j] * aD1;
        }
        #pragma unroll
        for (int msk = 1; msk < 16; msk <<= 1)
            #pragma unroll
            for (int j = 0; j < 4; ++j) {
                ps[j] += __shfl_xor(ps[j], msk);
                pd[j] += __shfl_xor(pd[j], msk);
            }
        if (l16 == 0) {
            #pragma unroll
            for (int j = 0; j < 4; ++j) {
                int row = row0 + wr * 64 + mf * 16 + 4 * lg + j;
                if (row < M) {
                    as1[row * 8 + hidx] = ps[j];
                    ad1[row * 8 + hidx] = pd[j];
                }
            }
        }
    }
}

// ---------------- agg1: wave per node, online softmax (single exp) ----------------

__global__ __launch_bounds__(256) void k_agg1(const float* __restrict__ h1,
                                              const float* __restrict__ as1,
                                              const float* __restrict__ ad1,
                                              const int* __restrict__ rowptr,
                                              const int* __restrict__ colx,
                                              const float* __restrict__ b1,
                                              float* __restrict__ hb, int Nn) {
    int lane = threadIdx.x & 63, w = threadIdx.x >> 6;
    int n = blockIdx.x * 4 + w;
    if (n >= Nn) return;
    int head = lane >> 3;
    float ad = ad1[n * 8 + head];
    int beg = rowptr[n], end = rowptr[n + 1];
    float m = -1e30f, s = 0.f;
    float4 acc = {0.f, 0.f, 0.f, 0.f};
    for (int i = beg; i < end; ++i) {
        int src = colx[i];
        float e = as1[src * 8 + head] + ad;
        e = e > 0.f ? e : 0.2f * e;
        float4 hv = *(const float4*)&h1[(size_t)src * 256 + lane * 4];
        if (e <= m) {
            float p = __expf(e - m);
            s += p;
            acc.x += p * hv.x; acc.y += p * hv.y;
            acc.z += p * hv.z; acc.w += p * hv.w;
        } else {
            float r = __expf(m - e);
            s = s * r + 1.f;
            acc.x = acc.x * r + hv.x; acc.y = acc.y * r + hv.y;
            acc.z = acc.z * r + hv.z; acc.w = acc.w * r + hv.w;
            m = e;
        }
    }
    float inv = 1.f / (s + 1e-16f);
    float4 bv = *(const float4*)&b1[lane * 4];
    float4 o = {acc.x * inv + bv.x, acc.y * inv + bv.y,
                acc.z * inv + bv.z, acc.w * inv + bv.w};
    *(float4*)&hb[(size_t)n * 256 + lane * 4] = o;
}

// ---------------- BatchNorm stats ----------------

__global__ __launch_bounds__(256) void k_bnstats(const float* __restrict__ hb,
                                                 float* __restrict__ bnsum,
                                                 float* __restrict__ bnssum, int Nn) {
    int c = threadIdx.x;
    float s = 0.f, ss = 0.f;
    for (int r = blockIdx.x; r < Nn; r += gridDim.x) {
        float v = hb[(size_t)r * 256 + c];
        s += v; ss += v * v;
    }
    atomicAdd(&bnsum[c], s);
    atomicAdd(&bnssum[c], ss);
}

__global__ void k_bnfinal(const float* __restrict__ bnsum, const float* __restrict__ bnssum,
                          const float* __restrict__ gamma, const float* __restrict__ beta,
                          float* __restrict__ scale, float* __restrict__ shift, int Nn) {
    int c = threadIdx.x;
    float mu = bnsum[c] / (float)Nn;
    float var = bnssum[c] / (float)Nn - mu * mu;
    float inv = rsqrtf(var + 1e-5f);
    float sc = gamma[c] * inv;
    scale[c] = sc;
    shift[c] = beta[c] - mu * sc;
}

// ---------------- GEMM2 (MFMA split-bf16) with fused BN+ELU prologue ----------------
// h2[M,40] = elu(bn(hb))[M,256] @ W2[256,40]. Block 128 rows, N=64 (40 valid).

__global__ __launch_bounds__(256) void k_gemm2(const float* __restrict__ H,
                                               const float* __restrict__ W2,
                                               const float* __restrict__ scale,
                                               const float* __restrict__ shift,
                                               float* __restrict__ h2, int M) {
    __shared__ short Ash[128][40];
    __shared__ short Asl[128][40];
    __shared__ short Bsh[64][40];
    __shared__ short Bsl[64][40];
    __shared__ float ssc[256], ssh[256];
    int t = threadIdx.x;
    ssc[t] = scale[t];
    ssh[t] = shift[t];
    int l = t & 63, w = t >> 6;
    int wr = w >> 1, wc = w & 1;
    int row0 = blockIdx.x * 128;
    int l16 = l & 15, lg = l >> 4;

    f32x4 zero = {0.f, 0.f, 0.f, 0.f};
    f32x4 acc[4][2];
    #pragma unroll
    for (int i = 0; i < 4; ++i) { acc[i][0] = zero; acc[i][1] = zero; }
    __syncthreads();

    for (int k0 = 0; k0 < 256; k0 += 32) {
        #pragma unroll
        for (int p = 0; p < 4; ++p) {
            int s = t + p * 256;
            int r = s >> 3, c4 = s & 7;
            int grow = row0 + r;
            float4 v = {0.f, 0.f, 0.f, 0.f};
            if (grow < M) v = *(const float4*)&H[(size_t)grow * 256 + k0 + c4 * 4];
            int c = k0 + c4 * 4;
            float e0 = v.x * ssc[c + 0] + ssh[c + 0];
            float e1 = v.y * ssc[c + 1] + ssh[c + 1];
            float e2 = v.z * ssc[c + 2] + ssh[c + 2];
            float e3 = v.w * ssc[c + 3] + ssh[c + 3];
            e0 = e0 > 0.f ? e0 : __expf(e0) - 1.f;
            e1 = e1 > 0.f ? e1 : __expf(e1) - 1.f;
            e2 = e2 > 0.f ? e2 : __expf(e2) - 1.f;
            e3 = e3 > 0.f ? e3 : __expf(e3) - 1.f;
            short h, lo2;
            bfsplit(e0, &h, &lo2); Ash[r][c4 * 4 + 0] = h; Asl[r][c4 * 4 + 0] = lo2;
            bfsplit(e1, &h, &lo2); Ash[r][c4 * 4 + 1] = h; Asl[r][c4 * 4 + 1] = lo2;
            bfsplit(e2, &h, &lo2); Ash[r][c4 * 4 + 2] = h; Asl[r][c4 * 4 + 2] = lo2;
            bfsplit(e3, &h, &lo2); Ash[r][c4 * 4 + 3] = h; Asl[r][c4 * 4 + 3] = lo2;
        }
        #pragma unroll
        for (int p = 0; p < 8; ++p) {
            int s = t + p * 256;          // 0..2047 : kk(32) x col(64)
            int kk = s >> 6, col = s & 63;
            float v = (col < 40) ? W2[(size_t)(k0 + kk) * 40 + col] : 0.f;
            short h, lo2;
            bfsplit(v, &h, &lo2);
            Bsh[col][kk] = h; Bsl[col][kk] = lo2;
        }
        __syncthreads();
        short8 ah[4], al[4], bh[2], bl[2];
        #pragma unroll
        for (int mf = 0; mf < 4; ++mf) {
            ah[mf] = *(const short8*)&Ash[wr * 64 + mf * 16 + l16][lg * 8];
            al[mf] = *(const short8*)&Asl[wr * 64 + mf * 16 + l16][lg * 8];
        }
        #pragma unroll
        for (int nf = 0; nf < 2; ++nf) {
            bh[nf] = *(const short8*)&Bsh[wc * 32 + nf * 16 + l16][lg * 8];
            bl[nf] = *(const short8*)&Bsl[wc * 32 + nf * 16 + l16][lg * 8];
        }
        #pragma unroll
        for (int mf = 0; mf < 4; ++mf)
            #pragma unroll
            for (int nf = 0; nf < 2; ++nf) {
                acc[mf][nf] = __builtin_amdgcn_mfma_f32_16x16x32_bf16(ah[mf], bh[nf], acc[mf][nf], 0, 0, 0);
                acc[mf][nf] = __builtin_amdgcn_mfma_f32_16x16x32_bf16(ah[mf], bl[nf], acc[mf][nf], 0, 0, 0);
                acc[mf][nf] = __builtin_amdgcn_mfma_f32_16x16x32_bf16(al[mf], bh[nf], acc[mf][nf], 0, 0, 0);
            }
        __syncthreads();
    }

    #pragma unroll
    for (int mf = 0; mf < 4; ++mf)
        #pragma unroll
        for (int nf = 0; nf < 2; ++nf)
            #pragma unroll
            for (int j = 0; j < 4; ++j) {
                int row = row0 + wr * 64 + mf * 16 + 4 * lg + j;
                int col = wc * 32 + nf * 16 + l16;
                if (row < M && col < 40)
                    h2[(size_t)row * 40 + col] = acc[mf][nf][j];
            }
}

// ---------------- alpha2 ----------------

__global__ void k_alpha2(const float* __restrict__ h2, const float* __restrict__ atts,
                         const float* __restrict__ attd, float* __restrict__ as2,
                         float* __restrict__ ad2, int Nn) {
    int n = blockIdx.x * THREADS + threadIdx.x;
    if (n >= Nn) return;
    const float4* hp = (const float4*)&h2[(size_t)n * 40];
    float s = 0.f, d = 0.f;
    #pragma unroll
    for (int j = 0; j < 10; ++j) {
        float4 v = hp[j];
        float4 a = ((const float4*)atts)[j];
        float4 b = ((const float4*)attd)[j];
        s += v.x * a.x + v.y * a.y + v.z * a.z + v.w * a.w;
        d += v.x * b.x + v.y * b.y + v.z * b.z + v.w * b.w;
    }
    as2[n] = s; ad2[n] = d;
}

// ---------------- agg2 ----------------

__global__ __launch_bounds__(256) void k_agg2(const float* __restrict__ h2,
                                              const float* __restrict__ as2,
                                              const float* __restrict__ ad2,
                                              const int* __restrict__ rowptr,
                                              const int* __restrict__ colx,
                                              const float* __restrict__ b2,
                                              float* __restrict__ out, int Nn) {
    int lane = threadIdx.x & 63, w = threadIdx.x >> 6;
    int n = blockIdx.x * 4 + w;
    if (n >= Nn) return;
    float ad = ad2[n];
    int beg = rowptr[n], end = rowptr[n + 1];
    int c = lane < 40 ? lane : 0;
    float m = -1e30f, s = 0.f, acc = 0.f;
    for (int i = beg; i < end; ++i) {
        int src = colx[i];
        float e = as2[src] + ad;
        e = e > 0.f ? e : 0.2f * e;
        float hv = h2[(size_t)src * 40 + c];
        if (e <= m) {
            float p = __expf(e - m);
            s += p; acc += p * hv;
        } else {
            float r = __expf(m - e);
            s = s * r + 1.f;
            acc = acc * r + hv;
            m = e;
        }
    }
    if (lane < 40) out[(size_t)n * 40 + lane] = acc / (s + 1e-16f) + b2[lane];
}

// ---------------- launch ----------------

static inline size_t rup(size_t x) { return (x + 255) & ~(size_t)255; }

extern "C" void kernel_launch(void* const* d_in, const int* in_sizes, int n_in,
                              void* d_out, int out_size, void* d_ws, size_t ws_size,
                              hipStream_t stream) {
    const float* x     = (const float*)d_in[0];
    const int*   ei    = (const int*)d_in[1];
    const float* W1    = (const float*)d_in[2];
    const float* atts1 = (const float*)d_in[3];
    const float* attd1 = (const float*)d_in[4];
    const float* b1    = (const float*)d_in[5];
    const float* gamma = (const float*)d_in[6];
    const float* beta  = (const float*)d_in[7];
    const float* W2    = (const float*)d_in[8];
    const float* atts2 = (const float*)d_in[9];
    const float* attd2 = (const float*)d_in[10];
    const float* b2    = (const float*)d_in[11];

    const int N = in_sizes[0] / 256;
    const int E = in_sizes[1] / 2;
    const int* srcv = ei;
    const int* dstv = ei + E;

    char* w = (char*)d_ws;
    float* h1 = (float*)w;      w += rup((size_t)N * 256 * 4);
    float* hb = (float*)w;      w += rup((size_t)N * 256 * 4);
    float* h2 = (float*)w;      w += rup((size_t)N * 40 * 4);
    float* as1 = (float*)w;     w += rup((size_t)N * 8 * 4);
    float* ad1 = (float*)w;     w += rup((size_t)N * 8 * 4);
    float* as2 = (float*)w;     w += rup((size_t)N * 4);
    float* ad2 = (float*)w;     w += rup((size_t)N * 4);
    int* rowptr = (int*)w;      w += rup((size_t)(N + 1) * 4);
    int* cursor = (int*)w;      w += rup((size_t)N * 4);
    int* colx = (int*)w;        w += rup((size_t)(E + N) * 4);
    int* partial = (int*)w;     w += rup(256 * 4);
    int* partoff = (int*)w;     w += rup(256 * 4);
    float* bn = (float*)w;      w += rup(1024 * 4);
    float* bnsum = bn, *bnssum = bn + 256, *scale = bn + 512, *shift = bn + 768;

    const int NB = (N + 255) / 256;   // <= 256 for N <= 65536

    // CSR build
    hipMemsetAsync(cursor, 0, (size_t)N * 4, stream);
    hipMemsetAsync(bn, 0, 512 * 4, stream);
    k_count<<<(E + THREADS - 1) / THREADS, THREADS, 0, stream>>>(dstv, E, cursor);
    k_scanA<<<NB, 256, 0, stream>>>(cursor, partial, N);
    k_scanB<<<1, 256, 0, stream>>>(partial, partoff, rowptr, NB, N);
    k_scanC<<<NB, 256, 0, stream>>>(cursor, partoff, rowptr, colx, N);
    k_scatter<<<(E + THREADS - 1) / THREADS, THREADS, 0, stream>>>(srcv, dstv, E, cursor, colx);

    // Layer 1: MFMA gemm + fused alpha
    dim3 g1((N + 127) / 128, 4);
    k_gemm1<<<g1, 256, 0, stream>>>(x, W1, atts1, attd1, h1, as1, ad1, N);
    k_agg1<<<(N + 3) / 4, 256, 0, stream>>>(h1, as1, ad1, rowptr, colx, b1, hb, N);

    // BatchNorm stats (ELU+apply fused into gemm2)
    k_bnstats<<<512, 256, 0, stream>>>(hb, bnsum, bnssum, N);
    k_bnfinal<<<1, 256, 0, stream>>>(bnsum, bnssum, gamma, beta, scale, shift, N);

    // Layer 2
    k_gemm2<<<(N + 127) / 128, 256, 0, stream>>>(hb, W2, scale, shift, h2, N);
    k_alpha2<<<(N + THREADS - 1) / THREADS, THREADS, 0, stream>>>(h2, atts2, attd2, as2, ad2, N);
    k_agg2<<<(N + 3) / 4, 256, 0, stream>>>(h2, as2, ad2, rowptr, colx, b2, (float*)d_out, N);
}

// Round 10
// 563.424 us; speedup vs baseline: 1.4590x; 1.0151x over previous
//
#include <hip/hip_runtime.h>
#include <hip/hip_bf16.h>
#include <hip/hip_fp16.h>

#define THREADS 256

typedef __attribute__((ext_vector_type(8))) short short8;
typedef __attribute__((ext_vector_type(4))) float f32x4;

__device__ inline unsigned short f2bf_rn(float f) {
    unsigned u = __float_as_uint(f);
    unsigned r = (u + 0x7FFF + ((u >> 16) & 1)) >> 16;
    return (unsigned short)r;
}
__device__ inline float bf2f(unsigned short s) {
    return __uint_as_float(((unsigned)s) << 16);
}
__device__ inline void bfsplit(float f, short* hi, short* lo) {
    unsigned short h = f2bf_rn(f);
    *hi = (short)h;
    *lo = (short)f2bf_rn(f - bf2f(h));
}

// ---------------- CSR build ----------------

__global__ void k_count(const int* __restrict__ dstv, int E, int* __restrict__ deg) {
    int e = blockIdx.x * THREADS + threadIdx.x;
    if (e < E) atomicAdd(&deg[dstv[e]], 1);
}

__global__ void k_scanA(const int* __restrict__ deg, int* __restrict__ partial, int Nn) {
    __shared__ int sm[256];
    int i = blockIdx.x * 256 + threadIdx.x;
    sm[threadIdx.x] = (i < Nn) ? deg[i] + 1 : 0;
    __syncthreads();
    for (int off = 128; off > 0; off >>= 1) {
        if (threadIdx.x < off) sm[threadIdx.x] += sm[threadIdx.x + off];
        __syncthreads();
    }
    if (threadIdx.x == 0) partial[blockIdx.x] = sm[0];
}

__global__ void k_scanB(const int* __restrict__ partial, int* __restrict__ partoff,
                        int* __restrict__ rowptr, int nb, int Nn) {
    __shared__ int sm[256];
    int t = threadIdx.x;
    int v = (t < nb) ? partial[t] : 0;
    sm[t] = v;
    __syncthreads();
    for (int off = 1; off < 256; off <<= 1) {
        int u = (t >= off) ? sm[t - off] : 0;
        __syncthreads();
        sm[t] += u;
        __syncthreads();
    }
    if (t < nb) partoff[t] = sm[t] - v;
    if (t == 255) rowptr[Nn] = sm[255];
}

__global__ void k_scanC(int* __restrict__ deg_cursor, const int* __restrict__ partoff,
                        int* __restrict__ rowptr, int* __restrict__ colx, int Nn) {
    __shared__ int sm[256];
    int t = threadIdx.x;
    int i = blockIdx.x * 256 + t;
    int d = (i < Nn) ? deg_cursor[i] : 0;
    int v = (i < Nn) ? d + 1 : 0;
    sm[t] = v;
    __syncthreads();
    for (int off = 1; off < 256; off <<= 1) {
        int u = (t >= off) ? sm[t - off] : 0;
        __syncthreads();
        sm[t] += u;
        __syncthreads();
    }
    int excl = sm[t] - v + partoff[blockIdx.x];
    if (i < Nn) {
        rowptr[i] = excl;
        colx[excl] = i;             // self loop first in segment
        deg_cursor[i] = excl + 1;   // scatter cursor
    }
}

__global__ void k_scatter(const int* __restrict__ srcv, const int* __restrict__ dstv,
                          int E, int* __restrict__ cursor, int* __restrict__ colx) {
    int e = blockIdx.x * THREADS + threadIdx.x;
    if (e >= E) return;
    int pos = atomicAdd(&cursor[dstv[e]], 1);
    colx[pos] = srcv[e];
}

// ---------------- GEMM1 (MFMA split-bf16) + fused alpha1, fp16 output ----------------
// h1[M,256] = x[M,256] @ W1[256,256]. Block 128 rows x 256 cols (full width),
// 512 threads = 8 waves (2x4), wave tile 64x64. A read exactly once.

__global__ __launch_bounds__(512) void k_gemm1(const float* __restrict__ A,
                                               const float* __restrict__ B,
                                               const float* __restrict__ attS,
                                               const float* __restrict__ attD,
                                               __half* __restrict__ C,
                                               float* __restrict__ as1,
                                               float* __restrict__ ad1, int M) {
    __shared__ short Ash[128][40];
    __shared__ short Asl[128][40];
    __shared__ short Bsh[256][40];
    __shared__ short Bsl[256][40];
    int t = threadIdx.x;
    int l = t & 63, w = t >> 6;          // 8 waves
    int wr = w >> 2, wc = w & 3;         // 2 x 4
    int row0 = blockIdx.x * 128;
    int l16 = l & 15, lg = l >> 4;

    f32x4 zero = {0.f, 0.f, 0.f, 0.f};
    f32x4 acc[4][4];
    #pragma unroll
    for (int i = 0; i < 4; ++i)
        #pragma unroll
        for (int j = 0; j < 4; ++j) acc[i][j] = zero;

    for (int k0 = 0; k0 < 256; k0 += 32) {
        // stage A: 128x32 fp32 -> hi/lo bf16 (1024 float4 slots / 512 thr)
        #pragma unroll
        for (int p = 0; p < 2; ++p) {
            int s = t + p * 512;
            int r = s >> 3, c4 = s & 7;
            int grow = row0 + r;
            float4 v = {0.f, 0.f, 0.f, 0.f};
            if (grow < M) v = *(const float4*)&A[(size_t)grow * 256 + k0 + c4 * 4];
            short h, lo2;
            bfsplit(v.x, &h, &lo2); Ash[r][c4 * 4 + 0] = h; Asl[r][c4 * 4 + 0] = lo2;
            bfsplit(v.y, &h, &lo2); Ash[r][c4 * 4 + 1] = h; Asl[r][c4 * 4 + 1] = lo2;
            bfsplit(v.z, &h, &lo2); Ash[r][c4 * 4 + 2] = h; Asl[r][c4 * 4 + 2] = lo2;
            bfsplit(v.w, &h, &lo2); Ash[r][c4 * 4 + 3] = h; Asl[r][c4 * 4 + 3] = lo2;
        }
        // stage B transposed [col][k]: 32x256 (2048 float4 slots / 512 thr)
        #pragma unroll
        for (int p = 0; p < 4; ++p) {
            int s = t + p * 512;
            int kk = s >> 6, c4 = s & 63;
            float4 v = *(const float4*)&B[(size_t)(k0 + kk) * 256 + c4 * 4];
            short h, lo2;
            bfsplit(v.x, &h, &lo2); Bsh[c4 * 4 + 0][kk] = h; Bsl[c4 * 4 + 0][kk] = lo2;
            bfsplit(v.y, &h, &lo2); Bsh[c4 * 4 + 1][kk] = h; Bsl[c4 * 4 + 1][kk] = lo2;
            bfsplit(v.z, &h, &lo2); Bsh[c4 * 4 + 2][kk] = h; Bsl[c4 * 4 + 2][kk] = lo2;
            bfsplit(v.w, &h, &lo2); Bsh[c4 * 4 + 3][kk] = h; Bsl[c4 * 4 + 3][kk] = lo2;
        }
        __syncthreads();
        #pragma unroll
        for (int mf = 0; mf < 4; ++mf) {
            short8 ah = *(const short8*)&Ash[wr * 64 + mf * 16 + l16][lg * 8];
            short8 al = *(const short8*)&Asl[wr * 64 + mf * 16 + l16][lg * 8];
            #pragma unroll
            for (int nf = 0; nf < 4; ++nf) {
                short8 bh = *(const short8*)&Bsh[wc * 64 + nf * 16 + l16][lg * 8];
                short8 bl = *(const short8*)&Bsl[wc * 64 + nf * 16 + l16][lg * 8];
                acc[mf][nf] = __builtin_amdgcn_mfma_f32_16x16x32_bf16(ah, bh, acc[mf][nf], 0, 0, 0);
                acc[mf][nf] = __builtin_amdgcn_mfma_f32_16x16x32_bf16(ah, bl, acc[mf][nf], 0, 0, 0);
                acc[mf][nf] = __builtin_amdgcn_mfma_f32_16x16x32_bf16(al, bh, acc[mf][nf], 0, 0, 0);
            }
        }
        __syncthreads();
    }

    // C write (fp16): row = wr*64 + mf*16 + 4*lg + j, col = wc*64 + nf*16 + l16
    #pragma unroll
    for (int mf = 0; mf < 4; ++mf)
        #pragma unroll
        for (int nf = 0; nf < 4; ++nf)
            #pragma unroll
            for (int j = 0; j < 4; ++j) {
                int row = row0 + wr * 64 + mf * 16 + 4 * lg + j;
                if (row < M)
                    C[(size_t)row * 256 + wc * 64 + nf * 16 + l16] =
                        __float2half(acc[mf][nf][j]);
            }

    // fused alpha: wave covers heads 2*wc and 2*wc+1 (cols wc*64 .. wc*64+63)
    #pragma unroll
    for (int hh = 0; hh < 2; ++hh) {
        int hidx = wc * 2 + hh;
        float aS0 = attS[hidx * 32 + l16],      aD0 = attD[hidx * 32 + l16];
        float aS1 = attS[hidx * 32 + 16 + l16], aD1 = attD[hidx * 32 + 16 + l16];
        #pragma unroll
        for (int mf = 0; mf < 4; ++mf) {
            float ps[4], pd[4];
            #pragma unroll
            for (int j = 0; j < 4; ++j) {
                ps[j] = acc[mf][2 * hh][j] * aS0 + acc[mf][2 * hh + 1][j] * aS1;
                pd[j] = acc[mf][2 * hh][j] * aD0 + acc[mf][2 * hh + 1][j] * aD1;
            }
            #pragma unroll
            for (int msk = 1; msk < 16; msk <<= 1)
                #pragma unroll
                for (int j = 0; j < 4; ++j) {
                    ps[j] += __shfl_xor(ps[j], msk);
                    pd[j] += __shfl_xor(pd[j], msk);
                }
            if (l16 == 0) {
                #pragma unroll
                for (int j = 0; j < 4; ++j) {
                    int row = row0 + wr * 64 + mf * 16 + 4 * lg + j;
                    if (row < M) {
                        as1[row * 8 + hidx] = ps[j];
                        ad1[row * 8 + hidx] = pd[j];
                    }
                }
            }
        }
    }
}

// ---------------- agg1: wave per node, fp16 gather (4 ch/lane), online softmax ----

__global__ __launch_bounds__(256) void k_agg1(const __half* __restrict__ h1,
                                              const float* __restrict__ as1,
                                              const float* __restrict__ ad1,
                                              const int* __restrict__ rowptr,
                                              const int* __restrict__ colx,
                                              const float* __restrict__ b1,
                                              float* __restrict__ hb, int Nn) {
    int lane = threadIdx.x & 63, w = threadIdx.x >> 6;
    int n = blockIdx.x * 4 + w;
    if (n >= Nn) return;
    int head = lane >> 3;                  // lane covers channels [4*lane, 4*lane+4)
    float ad = ad1[n * 8 + head];
    int beg = rowptr[n], end = rowptr[n + 1];
    float m = -1e30f, s = 0.f;
    float acc[4] = {};
    for (int i = beg; i < end; ++i) {
        int src = colx[i];
        float e = as1[src * 8 + head] + ad;
        e = e > 0.f ? e : 0.2f * e;        // leaky relu 0.2
        uint2 raw = *(const uint2*)&h1[(size_t)src * 256 + lane * 4];
        float2 f0 = __half22float2(*(__half2*)&raw.x);
        float2 f1 = __half22float2(*(__half2*)&raw.y);
        float hv[4] = {f0.x, f0.y, f1.x, f1.y};
        if (e <= m) {
            float p = __expf(e - m);
            s += p;
            #pragma unroll
            for (int q = 0; q < 4; ++q) acc[q] += p * hv[q];
        } else {
            float r = __expf(m - e);
            s = s * r + 1.f;
            #pragma unroll
            for (int q = 0; q < 4; ++q) acc[q] = acc[q] * r + hv[q];
            m = e;
        }
    }
    float inv = 1.f / (s + 1e-16f);
    float4 bv = *(const float4*)&b1[lane * 4];
    float4 o = {acc[0] * inv + bv.x, acc[1] * inv + bv.y,
                acc[2] * inv + bv.z, acc[3] * inv + bv.w};
    *(float4*)&hb[(size_t)n * 256 + lane * 4] = o;
}

// ---------------- BatchNorm stats ----------------

__global__ __launch_bounds__(256) void k_bnstats(const float* __restrict__ hb,
                                                 float* __restrict__ bnsum,
                                                 float* __restrict__ bnssum, int Nn) {
    int c = threadIdx.x;
    float s = 0.f, ss = 0.f;
    for (int r = blockIdx.x; r < Nn; r += gridDim.x) {
        float v = hb[(size_t)r * 256 + c];
        s += v; ss += v * v;
    }
    atomicAdd(&bnsum[c], s);
    atomicAdd(&bnssum[c], ss);
}

__global__ void k_bnfinal(const float* __restrict__ bnsum, const float* __restrict__ bnssum,
                          const float* __restrict__ gamma, const float* __restrict__ beta,
                          float* __restrict__ scale, float* __restrict__ shift, int Nn) {
    int c = threadIdx.x;
    float mu = bnsum[c] / (float)Nn;
    float var = bnssum[c] / (float)Nn - mu * mu;
    float inv = rsqrtf(var + 1e-5f);
    float sc = gamma[c] * inv;
    scale[c] = sc;
    shift[c] = beta[c] - mu * sc;
}

// ---------------- GEMM2 (MFMA split-bf16) with fused BN+ELU, fp16 output ----------------

__global__ __launch_bounds__(256) void k_gemm2(const float* __restrict__ H,
                                               const float* __restrict__ W2,
                                               const float* __restrict__ scale,
                                               const float* __restrict__ shift,
                                               __half* __restrict__ h2, int M) {
    __shared__ short Ash[128][40];
    __shared__ short Asl[128][40];
    __shared__ short Bsh[64][40];
    __shared__ short Bsl[64][40];
    __shared__ float ssc[256], ssh[256];
    int t = threadIdx.x;
    ssc[t] = scale[t];
    ssh[t] = shift[t];
    int l = t & 63, w = t >> 6;
    int wr = w >> 1, wc = w & 1;
    int row0 = blockIdx.x * 128;
    int l16 = l & 15, lg = l >> 4;

    f32x4 zero = {0.f, 0.f, 0.f, 0.f};
    f32x4 acc[4][2];
    #pragma unroll
    for (int i = 0; i < 4; ++i) { acc[i][0] = zero; acc[i][1] = zero; }
    __syncthreads();

    for (int k0 = 0; k0 < 256; k0 += 32) {
        #pragma unroll
        for (int p = 0; p < 4; ++p) {
            int s = t + p * 256;
            int r = s >> 3, c4 = s & 7;
            int grow = row0 + r;
            float4 v = {0.f, 0.f, 0.f, 0.f};
            if (grow < M) v = *(const float4*)&H[(size_t)grow * 256 + k0 + c4 * 4];
            int c = k0 + c4 * 4;
            float e0 = v.x * ssc[c + 0] + ssh[c + 0];
            float e1 = v.y * ssc[c + 1] + ssh[c + 1];
            float e2 = v.z * ssc[c + 2] + ssh[c + 2];
            float e3 = v.w * ssc[c + 3] + ssh[c + 3];
            e0 = e0 > 0.f ? e0 : __expf(e0) - 1.f;
            e1 = e1 > 0.f ? e1 : __expf(e1) - 1.f;
            e2 = e2 > 0.f ? e2 : __expf(e2) - 1.f;
            e3 = e3 > 0.f ? e3 : __expf(e3) - 1.f;
            short h, lo2;
            bfsplit(e0, &h, &lo2); Ash[r][c4 * 4 + 0] = h; Asl[r][c4 * 4 + 0] = lo2;
            bfsplit(e1, &h, &lo2); Ash[r][c4 * 4 + 1] = h; Asl[r][c4 * 4 + 1] = lo2;
            bfsplit(e2, &h, &lo2); Ash[r][c4 * 4 + 2] = h; Asl[r][c4 * 4 + 2] = lo2;
            bfsplit(e3, &h, &lo2); Ash[r][c4 * 4 + 3] = h; Asl[r][c4 * 4 + 3] = lo2;
        }
        #pragma unroll
        for (int p = 0; p < 8; ++p) {
            int s = t + p * 256;          // kk(32) x col(64)
            int kk = s >> 6, col = s & 63;
            float v = (col < 40) ? W2[(size_t)(k0 + kk) * 40 + col] : 0.f;
            short h, lo2;
            bfsplit(v, &h, &lo2);
            Bsh[col][kk] = h; Bsl[col][kk] = lo2;
        }
        __syncthreads();
        #pragma unroll
        for (int mf = 0; mf < 4; ++mf) {
            short8 ah = *(const short8*)&Ash[wr * 64 + mf * 16 + l16][lg * 8];
            short8 al = *(const short8*)&Asl[wr * 64 + mf * 16 + l16][lg * 8];
            #pragma unroll
            for (int nf = 0; nf < 2; ++nf) {
                short8 bh = *(const short8*)&Bsh[wc * 32 + nf * 16 + l16][lg * 8];
                short8 bl = *(const short8*)&Bsl[wc * 32 + nf * 16 + l16][lg * 8];
                acc[mf][nf] = __builtin_amdgcn_mfma_f32_16x16x32_bf16(ah, bh, acc[mf][nf], 0, 0, 0);
                acc[mf][nf] = __builtin_amdgcn_mfma_f32_16x16x32_bf16(ah, bl, acc[mf][nf], 0, 0, 0);
                acc[mf][nf] = __builtin_amdgcn_mfma_f32_16x16x32_bf16(al, bh, acc[mf][nf], 0, 0, 0);
            }
        }
        __syncthreads();
    }

    #pragma unroll
    for (int mf = 0; mf < 4; ++mf)
        #pragma unroll
        for (int nf = 0; nf < 2; ++nf)
            #pragma unroll
            for (int j = 0; j < 4; ++j) {
                int row = row0 + wr * 64 + mf * 16 + 4 * lg + j;
                int col = wc * 32 + nf * 16 + l16;
                if (row < M && col < 40)
                    h2[(size_t)row * 40 + col] = __float2half(acc[mf][nf][j]);
            }
}

// ---------------- alpha2 (fp16 h2) ----------------

__global__ void k_alpha2(const __half* __restrict__ h2, const float* __restrict__ atts,
                         const float* __restrict__ attd, float* __restrict__ as2,
                         float* __restrict__ ad2, int Nn) {
    int n = blockIdx.x * THREADS + threadIdx.x;
    if (n >= Nn) return;
    const __half2* hp = (const __half2*)&h2[(size_t)n * 40];
    float s = 0.f, d = 0.f;
    #pragma unroll
    for (int j = 0; j < 20; ++j) {
        float2 v = __half22float2(hp[j]);
        s += v.x * atts[2 * j] + v.y * atts[2 * j + 1];
        d += v.x * attd[2 * j] + v.y * attd[2 * j + 1];
    }
    as2[n] = s; ad2[n] = d;
}

// ---------------- agg2: wave per node, fp16 gather, C=40 ----------------

__global__ __launch_bounds__(256) void k_agg2(const __half* __restrict__ h2,
                                              const float* __restrict__ as2,
                                              const float* __restrict__ ad2,
                                              const int* __restrict__ rowptr,
                                              const int* __restrict__ colx,
                                              const float* __restrict__ b2,
                                              float* __restrict__ out, int Nn) {
    int lane = threadIdx.x & 63, w = threadIdx.x >> 6;
    int n = blockIdx.x * 4 + w;
    if (n >= Nn) return;
    float ad = ad2[n];
    int beg = rowptr[n], end = rowptr[n + 1];
    int c = lane < 40 ? lane : 0;
    float m = -1e30f, s = 0.f, acc = 0.f;
    for (int i = beg; i < end; ++i) {
        int src = colx[i];
        float e = as2[src] + ad;
        e = e > 0.f ? e : 0.2f * e;
        float hv = __half2float(h2[(size_t)src * 40 + c]);
        if (e <= m) {
            float p = __expf(e - m);
            s += p; acc += p * hv;
        } else {
            float r = __expf(m - e);
            s = s * r + 1.f;
            acc = acc * r + hv;
            m = e;
        }
    }
    if (lane < 40) out[(size_t)n * 40 + lane] = acc / (s + 1e-16f) + b2[lane];
}

// ---------------- launch ----------------

static inline size_t rup(size_t x) { return (x + 255) & ~(size_t)255; }

extern "C" void kernel_launch(void* const* d_in, const int* in_sizes, int n_in,
                              void* d_out, int out_size, void* d_ws, size_t ws_size,
                              hipStream_t stream) {
    const float* x     = (const float*)d_in[0];
    const int*   ei    = (const int*)d_in[1];
    const float* W1    = (const float*)d_in[2];
    const float* atts1 = (const float*)d_in[3];
    const float* attd1 = (const float*)d_in[4];
    const float* b1    = (const float*)d_in[5];
    const float* gamma = (const float*)d_in[6];
    const float* beta  = (const float*)d_in[7];
    const float* W2    = (const float*)d_in[8];
    const float* atts2 = (const float*)d_in[9];
    const float* attd2 = (const float*)d_in[10];
    const float* b2    = (const float*)d_in[11];

    const int N = in_sizes[0] / 256;
    const int E = in_sizes[1] / 2;
    const int* srcv = ei;
    const int* dstv = ei + E;

    char* w = (char*)d_ws;
    __half* h1 = (__half*)w;    w += rup((size_t)N * 256 * 2);
    float* hb = (float*)w;      w += rup((size_t)N * 256 * 4);
    __half* h2 = (__half*)w;    w += rup((size_t)N * 40 * 2);
    float* as1 = (float*)w;     w += rup((size_t)N * 8 * 4);
    float* ad1 = (float*)w;     w += rup((size_t)N * 8 * 4);
    float* as2 = (float*)w;     w += rup((size_t)N * 4);
    float* ad2 = (float*)w;     w += rup((size_t)N * 4);
    int* rowptr = (int*)w;      w += rup((size_t)(N + 1) * 4);
    int* cursor = (int*)w;      w += rup((size_t)N * 4);
    int* colx = (int*)w;        w += rup((size_t)(E + N) * 4);
    int* partial = (int*)w;     w += rup(256 * 4);
    int* partoff = (int*)w;     w += rup(256 * 4);
    float* bn = (float*)w;      w += rup(1024 * 4);
    float* bnsum = bn, *bnssum = bn + 256, *scale = bn + 512, *shift = bn + 768;

    const int NB = (N + 255) / 256;   // <= 256 for N <= 65536

    // CSR build
    hipMemsetAsync(cursor, 0, (size_t)N * 4, stream);
    hipMemsetAsync(bn, 0, 512 * 4, stream);
    k_count<<<(E + THREADS - 1) / THREADS, THREADS, 0, stream>>>(dstv, E, cursor);
    k_scanA<<<NB, 256, 0, stream>>>(cursor, partial, N);
    k_scanB<<<1, 256, 0, stream>>>(partial, partoff, rowptr, NB, N);
    k_scanC<<<NB, 256, 0, stream>>>(cursor, partoff, rowptr, colx, N);
    k_scatter<<<(E + THREADS - 1) / THREADS, THREADS, 0, stream>>>(srcv, dstv, E, cursor, colx);

    // Layer 1: MFMA gemm (full-width, A read once) + fused alpha, fp16 h1
    k_gemm1<<<(N + 127) / 128, 512, 0, stream>>>(x, W1, atts1, attd1, h1, as1, ad1, N);
    k_agg1<<<(N + 3) / 4, 256, 0, stream>>>(h1, as1, ad1, rowptr, colx, b1, hb, N);

    // BatchNorm stats (ELU+apply fused into gemm2)
    k_bnstats<<<512, 256, 0, stream>>>(hb, bnsum, bnssum, N);
    k_bnfinal<<<1, 256, 0, stream>>>(bnsum, bnssum, gamma, beta, scale, shift, N);

    // Layer 2
    k_gemm2<<<(N + 127) / 128, 256, 0, stream>>>(hb, W2, scale, shift, h2, N);
    k_alpha2<<<(N + THREADS - 1) / THREADS, THREADS, 0, stream>>>(h2, atts2, attd2, as2, ad2, N);
    k_agg2<<<(N + 3) / 4, 256, 0, stream>>>(h2, as2, ad2, rowptr, colx, b2, (float*)d_out, N);
}

// Round 13
// 495.902 us; speedup vs baseline: 1.6576x; 1.1362x over previous
//
#include <hip/hip_runtime.h>
#include <hip/hip_bf16.h>
#include <hip/hip_fp16.h>

#define THREADS 256

typedef __attribute__((ext_vector_type(8))) short short8;
typedef __attribute__((ext_vector_type(4))) float f32x4;

__device__ inline unsigned short f2bf_rn(float f) {
    unsigned u = __float_as_uint(f);
    unsigned r = (u + 0x7FFF + ((u >> 16) & 1)) >> 16;
    return (unsigned short)r;
}
__device__ inline float bf2f(unsigned short s) {
    return __uint_as_float(((unsigned)s) << 16);
}
__device__ inline void bfsplit(float f, short* hi, short* lo) {
    unsigned short h = f2bf_rn(f);
    *hi = (short)h;
    *lo = (short)f2bf_rn(f - bf2f(h));
}

// ---------------- CSR build ----------------

__global__ void k_count(const int* __restrict__ dstv, int E, int* __restrict__ deg) {
    int e = blockIdx.x * THREADS + threadIdx.x;
    if (e < E) atomicAdd(&deg[dstv[e]], 1);
}

__global__ void k_scanA(const int* __restrict__ deg, int* __restrict__ partial, int Nn) {
    __shared__ int sm[256];
    int i = blockIdx.x * 256 + threadIdx.x;
    sm[threadIdx.x] = (i < Nn) ? deg[i] + 1 : 0;
    __syncthreads();
    for (int off = 128; off > 0; off >>= 1) {
        if (threadIdx.x < off) sm[threadIdx.x] += sm[threadIdx.x + off];
        __syncthreads();
    }
    if (threadIdx.x == 0) partial[blockIdx.x] = sm[0];
}

__global__ void k_scanB(const int* __restrict__ partial, int* __restrict__ partoff,
                        int* __restrict__ rowptr, int nb, int Nn) {
    __shared__ int sm[256];
    int t = threadIdx.x;
    int v = (t < nb) ? partial[t] : 0;
    sm[t] = v;
    __syncthreads();
    for (int off = 1; off < 256; off <<= 1) {
        int u = (t >= off) ? sm[t - off] : 0;
        __syncthreads();
        sm[t] += u;
        __syncthreads();
    }
    if (t < nb) partoff[t] = sm[t] - v;
    if (t == 255) rowptr[Nn] = sm[255];
}

__global__ void k_scanC(int* __restrict__ deg_cursor, const int* __restrict__ partoff,
                        int* __restrict__ rowptr, int* __restrict__ colx, int Nn) {
    __shared__ int sm[256];
    int t = threadIdx.x;
    int i = blockIdx.x * 256 + t;
    int d = (i < Nn) ? deg_cursor[i] : 0;
    int v = (i < Nn) ? d + 1 : 0;
    sm[t] = v;
    __syncthreads();
    for (int off = 1; off < 256; off <<= 1) {
        int u = (t >= off) ? sm[t - off] : 0;
        __syncthreads();
        sm[t] += u;
        __syncthreads();
    }
    int excl = sm[t] - v + partoff[blockIdx.x];
    if (i < Nn) {
        rowptr[i] = excl;
        colx[excl] = i;             // self loop first in segment
        deg_cursor[i] = excl + 1;   // scatter cursor
    }
}

__global__ void k_scatter(const int* __restrict__ srcv, const int* __restrict__ dstv,
                          int E, int* __restrict__ cursor, int* __restrict__ colx) {
    int e = blockIdx.x * THREADS + threadIdx.x;
    if (e >= E) return;
    int pos = atomicAdd(&cursor[dstv[e]], 1);
    colx[pos] = srcv[e];
}

// ---------------- weight pre-pack: W[k][col] fp32 -> Wh/Wl[col][k] bf16 ----------------

__global__ void k_packW1(const float* __restrict__ W, short* __restrict__ Wh,
                         short* __restrict__ Wl) {
    int g = blockIdx.x * 256 + threadIdx.x;   // 0..8191
    int col = g >> 5, k8 = (g & 31) * 8;
    short8 h, l;
    #pragma unroll
    for (int i = 0; i < 8; ++i) {
        short hh, ll;
        bfsplit(W[(size_t)(k8 + i) * 256 + col], &hh, &ll);
        h[i] = hh; l[i] = ll;
    }
    *(short8*)&Wh[col * 256 + k8] = h;
    *(short8*)&Wl[col * 256 + k8] = l;
}

__global__ void k_packW2(const float* __restrict__ W, short* __restrict__ Wh,
                         short* __restrict__ Wl) {
    int g = blockIdx.x * 256 + threadIdx.x;   // 0..2047
    int col = g >> 5, k8 = (g & 31) * 8;
    short8 h, l;
    #pragma unroll
    for (int i = 0; i < 8; ++i) {
        short hh = 0, ll = 0;
        if (col < 40) bfsplit(W[(size_t)(k8 + i) * 40 + col], &hh, &ll);
        h[i] = hh; l[i] = ll;
    }
    *(short8*)&Wh[col * 256 + k8] = h;
    *(short8*)&Wl[col * 256 + k8] = l;
}

// ---------------- GEMM1 (MFMA split-bf16) + fused alpha1, fp16 output ----------------
// h1[M,256] = x[M,256] @ W1[256,256]. Block 64 rows x 256 cols, 512 threads =
// 8 waves; wave w covers cols w*32..w*32+31 (= head w), all 64 rows.
// A staged in LDS (read once); B fragments read directly from packed W1h/W1l.

__global__ __launch_bounds__(512) void k_gemm1(const float* __restrict__ A,
                                               const short* __restrict__ W1h,
                                               const short* __restrict__ W1l,
                                               const float* __restrict__ attS,
                                               const float* __restrict__ attD,
                                               __half* __restrict__ C,
                                               float* __restrict__ as1,
                                               float* __restrict__ ad1, int M) {
    __shared__ short Ash[64][40];
    __shared__ short Asl[64][40];
    int t = threadIdx.x;
    int l = t & 63, wc = t >> 6;         // 8 waves, wave = head
    int row0 = blockIdx.x * 64;
    int l16 = l & 15, lg = l >> 4;

    f32x4 zero = {0.f, 0.f, 0.f, 0.f};
    f32x4 acc[4][2];
    #pragma unroll
    for (int i = 0; i < 4; ++i) { acc[i][0] = zero; acc[i][1] = zero; }

    for (int k0 = 0; k0 < 256; k0 += 32) {
        // stage A: 64x32 fp32 -> hi/lo bf16 (512 float4 slots / 512 thr)
        {
            int r = t >> 3, c4 = t & 7;
            int grow = row0 + r;
            float4 v = {0.f, 0.f, 0.f, 0.f};
            if (grow < M) v = *(const float4*)&A[(size_t)grow * 256 + k0 + c4 * 4];
            short h, lo2;
            bfsplit(v.x, &h, &lo2); Ash[r][c4 * 4 + 0] = h; Asl[r][c4 * 4 + 0] = lo2;
            bfsplit(v.y, &h, &lo2); Ash[r][c4 * 4 + 1] = h; Asl[r][c4 * 4 + 1] = lo2;
            bfsplit(v.z, &h, &lo2); Ash[r][c4 * 4 + 2] = h; Asl[r][c4 * 4 + 2] = lo2;
            bfsplit(v.w, &h, &lo2); Ash[r][c4 * 4 + 3] = h; Asl[r][c4 * 4 + 3] = lo2;
        }
        // B fragments direct from packed global (L2-resident), overlap barrier
        short8 bh[2], bl[2];
        #pragma unroll
        for (int nf = 0; nf < 2; ++nf) {
            int col = wc * 32 + nf * 16 + l16;
            bh[nf] = *(const short8*)&W1h[col * 256 + k0 + lg * 8];
            bl[nf] = *(const short8*)&W1l[col * 256 + k0 + lg * 8];
        }
        __syncthreads();
        #pragma unroll
        for (int mf = 0; mf < 4; ++mf) {
            short8 ah = *(const short8*)&Ash[mf * 16 + l16][lg * 8];
            short8 al = *(const short8*)&Asl[mf * 16 + l16][lg * 8];
            #pragma unroll
            for (int nf = 0; nf < 2; ++nf) {
                acc[mf][nf] = __builtin_amdgcn_mfma_f32_16x16x32_bf16(ah, bh[nf], acc[mf][nf], 0, 0, 0);
                acc[mf][nf] = __builtin_amdgcn_mfma_f32_16x16x32_bf16(ah, bl[nf], acc[mf][nf], 0, 0, 0);
                acc[mf][nf] = __builtin_amdgcn_mfma_f32_16x16x32_bf16(al, bh[nf], acc[mf][nf], 0, 0, 0);
            }
        }
        __syncthreads();
    }

    // C write (fp16): row = mf*16 + 4*lg + j, col = wc*32 + nf*16 + l16
    #pragma unroll
    for (int mf = 0; mf < 4; ++mf)
        #pragma unroll
        for (int nf = 0; nf < 2; ++nf)
            #pragma unroll
            for (int j = 0; j < 4; ++j) {
                int row = row0 + mf * 16 + 4 * lg + j;
                if (row < M)
                    C[(size_t)row * 256 + wc * 32 + nf * 16 + l16] =
                        __float2half(acc[mf][nf][j]);
            }

    // fused alpha: wave wc owns head wc (cols wc*32..wc*32+31)
    {
        float aS0 = attS[wc * 32 + l16],      aD0 = attD[wc * 32 + l16];
        float aS1 = attS[wc * 32 + 16 + l16], aD1 = attD[wc * 32 + 16 + l16];
        #pragma unroll
        for (int mf = 0; mf < 4; ++mf) {
            float ps[4], pd[4];
            #pragma unroll
            for (int j = 0; j < 4; ++j) {
                ps[j] = acc[mf][0][j] * aS0 + acc[mf][1][j] * aS1;
                pd[j] = acc[mf][0][j] * aD0 + acc[mf][1][j] * aD1;
            }
            #pragma unroll
            for (int msk = 1; msk < 16; msk <<= 1)
                #pragma unroll
                for (int j = 0; j < 4; ++j) {
                    ps[j] += __shfl_xor(ps[j], msk);
                    pd[j] += __shfl_xor(pd[j], msk);
                }
            if (l16 == 0) {
                #pragma unroll
                for (int j = 0; j < 4; ++j) {
                    int row = row0 + mf * 16 + 4 * lg + j;
                    if (row < M) {
                        as1[row * 8 + wc] = ps[j];
                        ad1[row * 8 + wc] = pd[j];
                    }
                }
            }
        }
    }
}

// ---------------- agg1: wave per node, fp16 gather (4 ch/lane), online softmax ----

__global__ __launch_bounds__(256) void k_agg1(const __half* __restrict__ h1,
                                              const float* __restrict__ as1,
                                              const float* __restrict__ ad1,
                                              const int* __restrict__ rowptr,
                                              const int* __restrict__ colx,
                                              const float* __restrict__ b1,
                                              float* __restrict__ hb, int Nn) {
    int lane = threadIdx.x & 63, w = threadIdx.x >> 6;
    int n = blockIdx.x * 4 + w;
    if (n >= Nn) return;
    int head = lane >> 3;                  // lane covers channels [4*lane, 4*lane+4)
    float ad = ad1[n * 8 + head];
    int beg = rowptr[n], end = rowptr[n + 1];
    float m = -1e30f, s = 0.f;
    float acc[4] = {};
    for (int i = beg; i < end; ++i) {
        int src = colx[i];
        float e = as1[src * 8 + head] + ad;
        e = e > 0.f ? e : 0.2f * e;        // leaky relu 0.2
        uint2 raw = *(const uint2*)&h1[(size_t)src * 256 + lane * 4];
        float2 f0 = __half22float2(*(__half2*)&raw.x);
        float2 f1 = __half22float2(*(__half2*)&raw.y);
        float hv[4] = {f0.x, f0.y, f1.x, f1.y};
        if (e <= m) {
            float p = __expf(e - m);
            s += p;
            #pragma unroll
            for (int q = 0; q < 4; ++q) acc[q] += p * hv[q];
        } else {
            float r = __expf(m - e);
            s = s * r + 1.f;
            #pragma unroll
            for (int q = 0; q < 4; ++q) acc[q] = acc[q] * r + hv[q];
            m = e;
        }
    }
    float inv = 1.f / (s + 1e-16f);
    float4 bv = *(const float4*)&b1[lane * 4];
    float4 o = {acc[0] * inv + bv.x, acc[1] * inv + bv.y,
                acc[2] * inv + bv.z, acc[3] * inv + bv.w};
    *(float4*)&hb[(size_t)n * 256 + lane * 4] = o;
}

// ---------------- BatchNorm stats ----------------

__global__ __launch_bounds__(256) void k_bnstats(const float* __restrict__ hb,
                                                 float* __restrict__ bnsum,
                                                 float* __restrict__ bnssum, int Nn) {
    int c = threadIdx.x;
    float s = 0.f, ss = 0.f;
    for (int r = blockIdx.x; r < Nn; r += gridDim.x) {
        float v = hb[(size_t)r * 256 + c];
        s += v; ss += v * v;
    }
    atomicAdd(&bnsum[c], s);
    atomicAdd(&bnssum[c], ss);
}

__global__ void k_bnfinal(const float* __restrict__ bnsum, const float* __restrict__ bnssum,
                          const float* __restrict__ gamma, const float* __restrict__ beta,
                          float* __restrict__ scale, float* __restrict__ shift, int Nn) {
    int c = threadIdx.x;
    float mu = bnsum[c] / (float)Nn;
    float var = bnssum[c] / (float)Nn - mu * mu;
    float inv = rsqrtf(var + 1e-5f);
    float sc = gamma[c] * inv;
    scale[c] = sc;
    shift[c] = beta[c] - mu * sc;
}

// ---------------- GEMM2 (MFMA split-bf16), fused BN+ELU, fp16 output ----------------
// h2[M,40] = elu(bn(hb)) @ W2. Block 64 rows, 256 threads = 4 waves;
// wave w covers cols w*16..w*16+15 (cols >= 40 discarded at write).

__global__ __launch_bounds__(256) void k_gemm2(const float* __restrict__ H,
                                               const short* __restrict__ W2h,
                                               const short* __restrict__ W2l,
                                               const float* __restrict__ scale,
                                               const float* __restrict__ shift,
                                               __half* __restrict__ h2, int M) {
    __shared__ short Ash[64][40];
    __shared__ short Asl[64][40];
    __shared__ float ssc[256], ssh[256];
    int t = threadIdx.x;
    ssc[t] = scale[t];
    ssh[t] = shift[t];
    int l = t & 63, wc = t >> 6;         // 4 waves
    int row0 = blockIdx.x * 64;
    int l16 = l & 15, lg = l >> 4;

    f32x4 zero = {0.f, 0.f, 0.f, 0.f};
    f32x4 acc[4];
    #pragma unroll
    for (int i = 0; i < 4; ++i) acc[i] = zero;
    __syncthreads();

    for (int k0 = 0; k0 < 256; k0 += 32) {
        #pragma unroll
        for (int p = 0; p < 2; ++p) {
            int s = t + p * 256;          // 0..511
            int r = s >> 3, c4 = s & 7;
            int grow = row0 + r;
            float4 v = {0.f, 0.f, 0.f, 0.f};
            if (grow < M) v = *(const float4*)&H[(size_t)grow * 256 + k0 + c4 * 4];
            int c = k0 + c4 * 4;
            float e0 = v.x * ssc[c + 0] + ssh[c + 0];
            float e1 = v.y * ssc[c + 1] + ssh[c + 1];
            float e2 = v.z * ssc[c + 2] + ssh[c + 2];
            float e3 = v.w * ssc[c + 3] + ssh[c + 3];
            e0 = e0 > 0.f ? e0 : __expf(e0) - 1.f;
            e1 = e1 > 0.f ? e1 : __expf(e1) - 1.f;
            e2 = e2 > 0.f ? e2 : __expf(e2) - 1.f;
            e3 = e3 > 0.f ? e3 : __expf(e3) - 1.f;
            short h, lo2;
            bfsplit(e0, &h, &lo2); Ash[r][c4 * 4 + 0] = h; Asl[r][c4 * 4 + 0] = lo2;
            bfsplit(e1, &h, &lo2); Ash[r][c4 * 4 + 1] = h; Asl[r][c4 * 4 + 1] = lo2;
            bfsplit(e2, &h, &lo2); Ash[r][c4 * 4 + 2] = h; Asl[r][c4 * 4 + 2] = lo2;
            bfsplit(e3, &h, &lo2); Ash[r][c4 * 4 + 3] = h; Asl[r][c4 * 4 + 3] = lo2;
        }
        short8 bh, bl;
        {
            int col = wc * 16 + l16;      // 0..63
            bh = *(const short8*)&W2h[col * 256 + k0 + lg * 8];
            bl = *(const short8*)&W2l[col * 256 + k0 + lg * 8];
        }
        __syncthreads();
        #pragma unroll
        for (int mf = 0; mf < 4; ++mf) {
            short8 ah = *(const short8*)&Ash[mf * 16 + l16][lg * 8];
            short8 al = *(const short8*)&Asl[mf * 16 + l16][lg * 8];
            acc[mf] = __builtin_amdgcn_mfma_f32_16x16x32_bf16(ah, bh, acc[mf], 0, 0, 0);
            acc[mf] = __builtin_amdgcn_mfma_f32_16x16x32_bf16(ah, bl, acc[mf], 0, 0, 0);
            acc[mf] = __builtin_amdgcn_mfma_f32_16x16x32_bf16(al, bh, acc[mf], 0, 0, 0);
        }
        __syncthreads();
    }

    int col = wc * 16 + l16;
    #pragma unroll
    for (int mf = 0; mf < 4; ++mf)
        #pragma unroll
        for (int j = 0; j < 4; ++j) {
            int row = row0 + mf * 16 + 4 * lg + j;
            if (row < M && col < 40)
                h2[(size_t)row * 40 + col] = __float2half(acc[mf][j]);
        }
}

// ---------------- alpha2 (fp16 h2) ----------------

__global__ void k_alpha2(const __half* __restrict__ h2, const float* __restrict__ atts,
                         const float* __restrict__ attd, float* __restrict__ as2,
                         float* __restrict__ ad2, int Nn) {
    int n = blockIdx.x * THREADS + threadIdx.x;
    if (n >= Nn) return;
    const __half2* hp = (const __half2*)&h2[(size_t)n * 40];
    float s = 0.f, d = 0.f;
    #pragma unroll
    for (int j = 0; j < 20; ++j) {
        float2 v = __half22float2(hp[j]);
        s += v.x * atts[2 * j] + v.y * atts[2 * j + 1];
        d += v.x * attd[2 * j] + v.y * attd[2 * j + 1];
    }
    as2[n] = s; ad2[n] = d;
}

// ---------------- agg2: wave per node, fp16 gather, C=40 ----------------

__global__ __launch_bounds__(256) void k_agg2(const __half* __restrict__ h2,
                                              const float* __restrict__ as2,
                                              const float* __restrict__ ad2,
                                              const int* __restrict__ rowptr,
                                              const int* __restrict__ colx,
                                              const float* __restrict__ b2,
                                              float* __restrict__ out, int Nn) {
    int lane = threadIdx.x & 63, w = threadIdx.x >> 6;
    int n = blockIdx.x * 4 + w;
    if (n >= Nn) return;
    float ad = ad2[n];
    int beg = rowptr[n], end = rowptr[n + 1];
    int c = lane < 40 ? lane : 0;
    float m = -1e30f, s = 0.f, acc = 0.f;
    for (int i = beg; i < end; ++i) {
        int src = colx[i];
        float e = as2[src] + ad;
        e = e > 0.f ? e : 0.2f * e;
        float hv = __half2float(h2[(size_t)src * 40 + c]);
        if (e <= m) {
            float p = __expf(e - m);
            s += p; acc += p * hv;
        } else {
            float r = __expf(m - e);
            s = s * r + 1.f;
            acc = acc * r + hv;
            m = e;
        }
    }
    if (lane < 40) out[(size_t)n * 40 + lane] = acc / (s + 1e-16f) + b2[lane];
}

// ---------------- launch ----------------

static inline size_t rup(size_t x) { return (x + 255) & ~(size_t)255; }

extern "C" void kernel_launch(void* const* d_in, const int* in_sizes, int n_in,
                              void* d_out, int out_size, void* d_ws, size_t ws_size,
                              hipStream_t stream) {
    const float* x     = (const float*)d_in[0];
    const int*   ei    = (const int*)d_in[1];
    const float* W1    = (const float*)d_in[2];
    const float* atts1 = (const float*)d_in[3];
    const float* attd1 = (const float*)d_in[4];
    const float* b1    = (const float*)d_in[5];
    const float* gamma = (const float*)d_in[6];
    const float* beta  = (const float*)d_in[7];
    const float* W2    = (const float*)d_in[8];
    const float* atts2 = (const float*)d_in[9];
    const float* attd2 = (const float*)d_in[10];
    const float* b2    = (const float*)d_in[11];

    const int N = in_sizes[0] / 256;
    const int E = in_sizes[1] / 2;
    const int* srcv = ei;
    const int* dstv = ei + E;

    char* w = (char*)d_ws;
    __half* h1 = (__half*)w;    w += rup((size_t)N * 256 * 2);
    float* hb = (float*)w;      w += rup((size_t)N * 256 * 4);
    __half* h2 = (__half*)w;    w += rup((size_t)N * 40 * 2);
    float* as1 = (float*)w;     w += rup((size_t)N * 8 * 4);
    float* ad1 = (float*)w;     w += rup((size_t)N * 8 * 4);
    float* as2 = (float*)w;     w += rup((size_t)N * 4);
    float* ad2 = (float*)w;     w += rup((size_t)N * 4);
    int* rowptr = (int*)w;      w += rup((size_t)(N + 1) * 4);
    int* cursor = (int*)w;      w += rup((size_t)N * 4);
    int* colx = (int*)w;        w += rup((size_t)(E + N) * 4);
    int* partial = (int*)w;     w += rup(256 * 4);
    int* partoff = (int*)w;     w += rup(256 * 4);
    float* bn = (float*)w;      w += rup(1024 * 4);
    float* bnsum = bn, *bnssum = bn + 256, *scale = bn + 512, *shift = bn + 768;
    short* W1h = (short*)w;     w += rup(256 * 256 * 2);
    short* W1l = (short*)w;     w += rup(256 * 256 * 2);
    short* W2h = (short*)w;     w += rup(64 * 256 * 2);
    short* W2l = (short*)w;     w += rup(64 * 256 * 2);

    const int NB = (N + 255) / 256;   // <= 256 for N <= 65536

    // weight pre-pack (bit-identical bf16 hi/lo, transposed to [col][k])
    k_packW1<<<32, 256, 0, stream>>>(W1, W1h, W1l);
    k_packW2<<<8, 256, 0, stream>>>(W2, W2h, W2l);

    // CSR build
    hipMemsetAsync(cursor, 0, (size_t)N * 4, stream);
    hipMemsetAsync(bn, 0, 512 * 4, stream);
    k_count<<<(E + THREADS - 1) / THREADS, THREADS, 0, stream>>>(dstv, E, cursor);
    k_scanA<<<NB, 256, 0, stream>>>(cursor, partial, N);
    k_scanB<<<1, 256, 0, stream>>>(partial, partoff, rowptr, NB, N);
    k_scanC<<<NB, 256, 0, stream>>>(cursor, partoff, rowptr, colx, N);
    k_scatter<<<(E + THREADS - 1) / THREADS, THREADS, 0, stream>>>(srcv, dstv, E, cursor, colx);

    // Layer 1
    k_gemm1<<<(N + 63) / 64, 512, 0, stream>>>(x, W1h, W1l, atts1, attd1, h1, as1, ad1, N);
    k_agg1<<<(N + 3) / 4, 256, 0, stream>>>(h1, as1, ad1, rowptr, colx, b1, hb, N);

    // BatchNorm stats (ELU+apply fused into gemm2)
    k_bnstats<<<512, 256, 0, stream>>>(hb, bnsum, bnssum, N);
    k_bnfinal<<<1, 256, 0, stream>>>(bnsum, bnssum, gamma, beta, scale, shift, N);

    // Layer 2
    k_gemm2<<<(N + 63) / 64, 256, 0, stream>>>(hb, W2h, W2l, scale, shift, h2, N);
    k_alpha2<<<(N + THREADS - 1) / THREADS, THREADS, 0, stream>>>(h2, atts2, attd2, as2, ad2, N);
    k_agg2<<<(N + 3) / 4, 256, 0, stream>>>(h2, as2, ad2, rowptr, colx, b2, (float*)d_out, N);
}

// Round 14
// 411.175 us; speedup vs baseline: 1.9992x; 1.2061x over previous
//
#include <hip/hip_runtime.h>
#include <hip/hip_bf16.h>
#include <hip/hip_fp16.h>

#define THREADS 256

typedef __attribute__((ext_vector_type(8))) short short8;
typedef __attribute__((ext_vector_type(4))) float f32x4;

__device__ inline unsigned short f2bf_rn(float f) {
    unsigned u = __float_as_uint(f);
    unsigned r = (u + 0x7FFF + ((u >> 16) & 1)) >> 16;
    return (unsigned short)r;
}
__device__ inline float bf2f(unsigned short s) {
    return __uint_as_float(((unsigned)s) << 16);
}
__device__ inline void bfsplit(float f, short* hi, short* lo) {
    unsigned short h = f2bf_rn(f);
    *hi = (short)h;
    *lo = (short)f2bf_rn(f - bf2f(h));
}

// ---------------- CSR build ----------------

__global__ void k_count(const int* __restrict__ dstv, int E, int* __restrict__ deg) {
    int e = blockIdx.x * THREADS + threadIdx.x;
    if (e < E) atomicAdd(&deg[dstv[e]], 1);
}

__global__ void k_scanA(const int* __restrict__ deg, int* __restrict__ partial, int Nn) {
    __shared__ int sm[256];
    int i = blockIdx.x * 256 + threadIdx.x;
    sm[threadIdx.x] = (i < Nn) ? deg[i] + 1 : 0;
    __syncthreads();
    for (int off = 128; off > 0; off >>= 1) {
        if (threadIdx.x < off) sm[threadIdx.x] += sm[threadIdx.x + off];
        __syncthreads();
    }
    if (threadIdx.x == 0) partial[blockIdx.x] = sm[0];
}

__global__ void k_scanB(const int* __restrict__ partial, int* __restrict__ partoff,
                        int* __restrict__ rowptr, int nb, int Nn) {
    __shared__ int sm[256];
    int t = threadIdx.x;
    int v = (t < nb) ? partial[t] : 0;
    sm[t] = v;
    __syncthreads();
    for (int off = 1; off < 256; off <<= 1) {
        int u = (t >= off) ? sm[t - off] : 0;
        __syncthreads();
        sm[t] += u;
        __syncthreads();
    }
    if (t < nb) partoff[t] = sm[t] - v;
    if (t == 255) rowptr[Nn] = sm[255];
}

__global__ void k_scanC(int* __restrict__ deg_cursor, const int* __restrict__ partoff,
                        int* __restrict__ rowptr, int* __restrict__ colx, int Nn) {
    __shared__ int sm[256];
    int t = threadIdx.x;
    int i = blockIdx.x * 256 + t;
    int d = (i < Nn) ? deg_cursor[i] : 0;
    int v = (i < Nn) ? d + 1 : 0;
    sm[t] = v;
    __syncthreads();
    for (int off = 1; off < 256; off <<= 1) {
        int u = (t >= off) ? sm[t - off] : 0;
        __syncthreads();
        sm[t] += u;
        __syncthreads();
    }
    int excl = sm[t] - v + partoff[blockIdx.x];
    if (i < Nn) {
        rowptr[i] = excl;
        colx[excl] = i;             // self loop first in segment
        deg_cursor[i] = excl + 1;   // scatter cursor
    }
}

__global__ void k_scatter(const int* __restrict__ srcv, const int* __restrict__ dstv,
                          int E, int* __restrict__ cursor, int* __restrict__ colx) {
    int e = blockIdx.x * THREADS + threadIdx.x;
    if (e >= E) return;
    int pos = atomicAdd(&cursor[dstv[e]], 1);
    colx[pos] = srcv[e];
}

// ---------------- weight pre-pack: W[k][col] fp32 -> Wh/Wl[col][k] bf16 ----------------

__global__ void k_packW1(const float* __restrict__ W, short* __restrict__ Wh,
                         short* __restrict__ Wl) {
    int g = blockIdx.x * 256 + threadIdx.x;   // 0..8191
    int col = g >> 5, k8 = (g & 31) * 8;
    short8 h, l;
    #pragma unroll
    for (int i = 0; i < 8; ++i) {
        short hh, ll;
        bfsplit(W[(size_t)(k8 + i) * 256 + col], &hh, &ll);
        h[i] = hh; l[i] = ll;
    }
    *(short8*)&Wh[col * 256 + k8] = h;
    *(short8*)&Wl[col * 256 + k8] = l;
}

__global__ void k_packW2(const float* __restrict__ W, short* __restrict__ Wh,
                         short* __restrict__ Wl) {
    int g = blockIdx.x * 256 + threadIdx.x;   // 0..2047
    int col = g >> 5, k8 = (g & 31) * 8;
    short8 h, l;
    #pragma unroll
    for (int i = 0; i < 8; ++i) {
        short hh = 0, ll = 0;
        if (col < 40) bfsplit(W[(size_t)(k8 + i) * 40 + col], &hh, &ll);
        h[i] = hh; l[i] = ll;
    }
    *(short8*)&Wh[col * 256 + k8] = h;
    *(short8*)&Wl[col * 256 + k8] = l;
}

// ---------------- GEMM1 (MFMA split-bf16) + fused alpha1, fp16 output ----------------
// h1[M,256] = x[M,256] @ W1[256,256]. Block 64 rows x 256 cols, 512 threads =
// 8 waves; wave w covers cols w*32..w*32+31 (= head w), all 64 rows.
// A staged in LDS (read once); B fragments read directly from packed W1h/W1l.

__global__ __launch_bounds__(512) void k_gemm1(const float* __restrict__ A,
                                               const short* __restrict__ W1h,
                                               const short* __restrict__ W1l,
                                               const float* __restrict__ attS,
                                               const float* __restrict__ attD,
                                               __half* __restrict__ C,
                                               float* __restrict__ as1,
                                               float* __restrict__ ad1, int M) {
    __shared__ short Ash[64][40];
    __shared__ short Asl[64][40];
    int t = threadIdx.x;
    int l = t & 63, wc = t >> 6;         // 8 waves, wave = head
    int row0 = blockIdx.x * 64;
    int l16 = l & 15, lg = l >> 4;

    f32x4 zero = {0.f, 0.f, 0.f, 0.f};
    f32x4 acc[4][2];
    #pragma unroll
    for (int i = 0; i < 4; ++i) { acc[i][0] = zero; acc[i][1] = zero; }

    for (int k0 = 0; k0 < 256; k0 += 32) {
        // stage A: 64x32 fp32 -> hi/lo bf16 (512 float4 slots / 512 thr)
        {
            int r = t >> 3, c4 = t & 7;
            int grow = row0 + r;
            float4 v = {0.f, 0.f, 0.f, 0.f};
            if (grow < M) v = *(const float4*)&A[(size_t)grow * 256 + k0 + c4 * 4];
            short h, lo2;
            bfsplit(v.x, &h, &lo2); Ash[r][c4 * 4 + 0] = h; Asl[r][c4 * 4 + 0] = lo2;
            bfsplit(v.y, &h, &lo2); Ash[r][c4 * 4 + 1] = h; Asl[r][c4 * 4 + 1] = lo2;
            bfsplit(v.z, &h, &lo2); Ash[r][c4 * 4 + 2] = h; Asl[r][c4 * 4 + 2] = lo2;
            bfsplit(v.w, &h, &lo2); Ash[r][c4 * 4 + 3] = h; Asl[r][c4 * 4 + 3] = lo2;
        }
        // B fragments direct from packed global (L2-resident), overlap barrier
        short8 bh[2], bl[2];
        #pragma unroll
        for (int nf = 0; nf < 2; ++nf) {
            int col = wc * 32 + nf * 16 + l16;
            bh[nf] = *(const short8*)&W1h[col * 256 + k0 + lg * 8];
            bl[nf] = *(const short8*)&W1l[col * 256 + k0 + lg * 8];
        }
        __syncthreads();
        #pragma unroll
        for (int mf = 0; mf < 4; ++mf) {
            short8 ah = *(const short8*)&Ash[mf * 16 + l16][lg * 8];
            short8 al = *(const short8*)&Asl[mf * 16 + l16][lg * 8];
            #pragma unroll
            for (int nf = 0; nf < 2; ++nf) {
                acc[mf][nf] = __builtin_amdgcn_mfma_f32_16x16x32_bf16(ah, bh[nf], acc[mf][nf], 0, 0, 0);
                acc[mf][nf] = __builtin_amdgcn_mfma_f32_16x16x32_bf16(ah, bl[nf], acc[mf][nf], 0, 0, 0);
                acc[mf][nf] = __builtin_amdgcn_mfma_f32_16x16x32_bf16(al, bh[nf], acc[mf][nf], 0, 0, 0);
            }
        }
        __syncthreads();
    }

    // C write (fp16): row = mf*16 + 4*lg + j, col = wc*32 + nf*16 + l16
    #pragma unroll
    for (int mf = 0; mf < 4; ++mf)
        #pragma unroll
        for (int nf = 0; nf < 2; ++nf)
            #pragma unroll
            for (int j = 0; j < 4; ++j) {
                int row = row0 + mf * 16 + 4 * lg + j;
                if (row < M)
                    C[(size_t)row * 256 + wc * 32 + nf * 16 + l16] =
                        __float2half(acc[mf][nf][j]);
            }

    // fused alpha: wave wc owns head wc (cols wc*32..wc*32+31)
    {
        float aS0 = attS[wc * 32 + l16],      aD0 = attD[wc * 32 + l16];
        float aS1 = attS[wc * 32 + 16 + l16], aD1 = attD[wc * 32 + 16 + l16];
        #pragma unroll
        for (int mf = 0; mf < 4; ++mf) {
            float ps[4], pd[4];
            #pragma unroll
            for (int j = 0; j < 4; ++j) {
                ps[j] = acc[mf][0][j] * aS0 + acc[mf][1][j] * aS1;
                pd[j] = acc[mf][0][j] * aD0 + acc[mf][1][j] * aD1;
            }
            #pragma unroll
            for (int msk = 1; msk < 16; msk <<= 1)
                #pragma unroll
                for (int j = 0; j < 4; ++j) {
                    ps[j] += __shfl_xor(ps[j], msk);
                    pd[j] += __shfl_xor(pd[j], msk);
                }
            if (l16 == 0) {
                #pragma unroll
                for (int j = 0; j < 4; ++j) {
                    int row = row0 + mf * 16 + 4 * lg + j;
                    if (row < M) {
                        as1[row * 8 + wc] = ps[j];
                        ad1[row * 8 + wc] = pd[j];
                    }
                }
            }
        }
    }
}

// ---- agg1: wave per node, fp16 gather, 4-edge unrolled branchless online softmax ----

__global__ __launch_bounds__(256) void k_agg1(const __half* __restrict__ h1,
                                              const float* __restrict__ as1,
                                              const float* __restrict__ ad1,
                                              const int* __restrict__ rowptr,
                                              const int* __restrict__ colx,
                                              const float* __restrict__ b1,
                                              float* __restrict__ hb, int Nn) {
    int lane = threadIdx.x & 63, w = threadIdx.x >> 6;
    int n = blockIdx.x * 4 + w;
    if (n >= Nn) return;
    int head = lane >> 3;                  // lane covers channels [4*lane, 4*lane+4)
    float ad = ad1[n * 8 + head];
    int beg = rowptr[n], end = rowptr[n + 1];
    float m = -1e30f, s = 0.f;
    float acc[4] = {};
    int i = beg;
    for (; i + 3 < end; i += 4) {
        int s0 = colx[i], s1 = colx[i + 1], s2 = colx[i + 2], s3 = colx[i + 3];
        uint2 r0 = *(const uint2*)&h1[(size_t)s0 * 256 + lane * 4];
        uint2 r1 = *(const uint2*)&h1[(size_t)s1 * 256 + lane * 4];
        uint2 r2 = *(const uint2*)&h1[(size_t)s2 * 256 + lane * 4];
        uint2 r3 = *(const uint2*)&h1[(size_t)s3 * 256 + lane * 4];
        float e0 = as1[s0 * 8 + head] + ad;
        float e1 = as1[s1 * 8 + head] + ad;
        float e2 = as1[s2 * 8 + head] + ad;
        float e3 = as1[s3 * 8 + head] + ad;
        e0 = e0 > 0.f ? e0 : 0.2f * e0;
        e1 = e1 > 0.f ? e1 : 0.2f * e1;
        e2 = e2 > 0.f ? e2 : 0.2f * e2;
        e3 = e3 > 0.f ? e3 : 0.2f * e3;
        float nm = fmaxf(fmaxf(m, fmaxf(e0, e1)), fmaxf(e2, e3));
        float r  = __expf(m - nm);
        float p0 = __expf(e0 - nm), p1 = __expf(e1 - nm);
        float p2 = __expf(e2 - nm), p3 = __expf(e3 - nm);
        float2 f00 = __half22float2(*(__half2*)&r0.x), f01 = __half22float2(*(__half2*)&r0.y);
        float2 f10 = __half22float2(*(__half2*)&r1.x), f11 = __half22float2(*(__half2*)&r1.y);
        float2 f20 = __half22float2(*(__half2*)&r2.x), f21 = __half22float2(*(__half2*)&r2.y);
        float2 f30 = __half22float2(*(__half2*)&r3.x), f31 = __half22float2(*(__half2*)&r3.y);
        float hv0[4] = {f00.x, f00.y, f01.x, f01.y};
        float hv1[4] = {f10.x, f10.y, f11.x, f11.y};
        float hv2[4] = {f20.x, f20.y, f21.x, f21.y};
        float hv3[4] = {f30.x, f30.y, f31.x, f31.y};
        s = s * r + (p0 + p1) + (p2 + p3);
        #pragma unroll
        for (int q = 0; q < 4; ++q)
            acc[q] = acc[q] * r + (p0 * hv0[q] + p1 * hv1[q]) + (p2 * hv2[q] + p3 * hv3[q]);
        m = nm;
    }
    for (; i < end; ++i) {
        int s0 = colx[i];
        uint2 raw = *(const uint2*)&h1[(size_t)s0 * 256 + lane * 4];
        float e = as1[s0 * 8 + head] + ad;
        e = e > 0.f ? e : 0.2f * e;
        float nm = fmaxf(m, e);
        float r = __expf(m - nm);
        float p = __expf(e - nm);
        float2 f0 = __half22float2(*(__half2*)&raw.x);
        float2 f1 = __half22float2(*(__half2*)&raw.y);
        float hv[4] = {f0.x, f0.y, f1.x, f1.y};
        s = s * r + p;
        #pragma unroll
        for (int q = 0; q < 4; ++q) acc[q] = acc[q] * r + p * hv[q];
        m = nm;
    }
    float inv = 1.f / (s + 1e-16f);
    float4 bv = *(const float4*)&b1[lane * 4];
    float4 o = {acc[0] * inv + bv.x, acc[1] * inv + bv.y,
                acc[2] * inv + bv.z, acc[3] * inv + bv.w};
    *(float4*)&hb[(size_t)n * 256 + lane * 4] = o;
}

// ---------------- BatchNorm stats ----------------

__global__ __launch_bounds__(256) void k_bnstats(const float* __restrict__ hb,
                                                 float* __restrict__ bnsum,
                                                 float* __restrict__ bnssum, int Nn) {
    int c = threadIdx.x;
    float s = 0.f, ss = 0.f;
    for (int r = blockIdx.x; r < Nn; r += gridDim.x) {
        float v = hb[(size_t)r * 256 + c];
        s += v; ss += v * v;
    }
    atomicAdd(&bnsum[c], s);
    atomicAdd(&bnssum[c], ss);
}

__global__ void k_bnfinal(const float* __restrict__ bnsum, const float* __restrict__ bnssum,
                          const float* __restrict__ gamma, const float* __restrict__ beta,
                          float* __restrict__ scale, float* __restrict__ shift, int Nn) {
    int c = threadIdx.x;
    float mu = bnsum[c] / (float)Nn;
    float var = bnssum[c] / (float)Nn - mu * mu;
    float inv = rsqrtf(var + 1e-5f);
    float sc = gamma[c] * inv;
    scale[c] = sc;
    shift[c] = beta[c] - mu * sc;
}

// ---------------- GEMM2 (MFMA split-bf16), fused BN+ELU, fp16 output ----------------
// h2[M,40] = elu(bn(hb)) @ W2. Block 64 rows, 256 threads = 4 waves;
// wave w covers cols w*16..w*16+15 (cols >= 40 discarded at write).

__global__ __launch_bounds__(256) void k_gemm2(const float* __restrict__ H,
                                               const short* __restrict__ W2h,
                                               const short* __restrict__ W2l,
                                               const float* __restrict__ scale,
                                               const float* __restrict__ shift,
                                               __half* __restrict__ h2, int M) {
    __shared__ short Ash[64][40];
    __shared__ short Asl[64][40];
    __shared__ float ssc[256], ssh[256];
    int t = threadIdx.x;
    ssc[t] = scale[t];
    ssh[t] = shift[t];
    int l = t & 63, wc = t >> 6;         // 4 waves
    int row0 = blockIdx.x * 64;
    int l16 = l & 15, lg = l >> 4;

    f32x4 zero = {0.f, 0.f, 0.f, 0.f};
    f32x4 acc[4];
    #pragma unroll
    for (int i = 0; i < 4; ++i) acc[i] = zero;
    __syncthreads();

    for (int k0 = 0; k0 < 256; k0 += 32) {
        #pragma unroll
        for (int p = 0; p < 2; ++p) {
            int s = t + p * 256;          // 0..511
            int r = s >> 3, c4 = s & 7;
            int grow = row0 + r;
            float4 v = {0.f, 0.f, 0.f, 0.f};
            if (grow < M) v = *(const float4*)&H[(size_t)grow * 256 + k0 + c4 * 4];
            int c = k0 + c4 * 4;
            float e0 = v.x * ssc[c + 0] + ssh[c + 0];
            float e1 = v.y * ssc[c + 1] + ssh[c + 1];
            float e2 = v.z * ssc[c + 2] + ssh[c + 2];
            float e3 = v.w * ssc[c + 3] + ssh[c + 3];
            e0 = e0 > 0.f ? e0 : __expf(e0) - 1.f;
            e1 = e1 > 0.f ? e1 : __expf(e1) - 1.f;
            e2 = e2 > 0.f ? e2 : __expf(e2) - 1.f;
            e3 = e3 > 0.f ? e3 : __expf(e3) - 1.f;
            short h, lo2;
            bfsplit(e0, &h, &lo2); Ash[r][c4 * 4 + 0] = h; Asl[r][c4 * 4 + 0] = lo2;
            bfsplit(e1, &h, &lo2); Ash[r][c4 * 4 + 1] = h; Asl[r][c4 * 4 + 1] = lo2;
            bfsplit(e2, &h, &lo2); Ash[r][c4 * 4 + 2] = h; Asl[r][c4 * 4 + 2] = lo2;
            bfsplit(e3, &h, &lo2); Ash[r][c4 * 4 + 3] = h; Asl[r][c4 * 4 + 3] = lo2;
        }
        short8 bh, bl;
        {
            int col = wc * 16 + l16;      // 0..63
            bh = *(const short8*)&W2h[col * 256 + k0 + lg * 8];
            bl = *(const short8*)&W2l[col * 256 + k0 + lg * 8];
        }
        __syncthreads();
        #pragma unroll
        for (int mf = 0; mf < 4; ++mf) {
            short8 ah = *(const short8*)&Ash[mf * 16 + l16][lg * 8];
            short8 al = *(const short8*)&Asl[mf * 16 + l16][lg * 8];
            acc[mf] = __builtin_amdgcn_mfma_f32_16x16x32_bf16(ah, bh, acc[mf], 0, 0, 0);
            acc[mf] = __builtin_amdgcn_mfma_f32_16x16x32_bf16(ah, bl, acc[mf], 0, 0, 0);
            acc[mf] = __builtin_amdgcn_mfma_f32_16x16x32_bf16(al, bh, acc[mf], 0, 0, 0);
        }
        __syncthreads();
    }

    int col = wc * 16 + l16;
    #pragma unroll
    for (int mf = 0; mf < 4; ++mf)
        #pragma unroll
        for (int j = 0; j < 4; ++j) {
            int row = row0 + mf * 16 + 4 * lg + j;
            if (row < M && col < 40)
                h2[(size_t)row * 40 + col] = __float2half(acc[mf][j]);
        }
}

// ---------------- alpha2 (fp16 h2) ----------------

__global__ void k_alpha2(const __half* __restrict__ h2, const float* __restrict__ atts,
                         const float* __restrict__ attd, float* __restrict__ as2,
                         float* __restrict__ ad2, int Nn) {
    int n = blockIdx.x * THREADS + threadIdx.x;
    if (n >= Nn) return;
    const __half2* hp = (const __half2*)&h2[(size_t)n * 40];
    float s = 0.f, d = 0.f;
    #pragma unroll
    for (int j = 0; j < 20; ++j) {
        float2 v = __half22float2(hp[j]);
        s += v.x * atts[2 * j] + v.y * atts[2 * j + 1];
        d += v.x * attd[2 * j] + v.y * attd[2 * j + 1];
    }
    as2[n] = s; ad2[n] = d;
}

// ---- agg2: wave per node, fp16 gather, 4-edge unrolled branchless, C=40 ----

__global__ __launch_bounds__(256) void k_agg2(const __half* __restrict__ h2,
                                              const float* __restrict__ as2,
                                              const float* __restrict__ ad2,
                                              const int* __restrict__ rowptr,
                                              const int* __restrict__ colx,
                                              const float* __restrict__ b2,
                                              float* __restrict__ out, int Nn) {
    int lane = threadIdx.x & 63, w = threadIdx.x >> 6;
    int n = blockIdx.x * 4 + w;
    if (n >= Nn) return;
    float ad = ad2[n];
    int beg = rowptr[n], end = rowptr[n + 1];
    int c = lane < 40 ? lane : 0;
    float m = -1e30f, s = 0.f, acc = 0.f;
    int i = beg;
    for (; i + 3 < end; i += 4) {
        int s0 = colx[i], s1 = colx[i + 1], s2 = colx[i + 2], s3 = colx[i + 3];
        float h0 = __half2float(h2[(size_t)s0 * 40 + c]);
        float h1v = __half2float(h2[(size_t)s1 * 40 + c]);
        float h2v = __half2float(h2[(size_t)s2 * 40 + c]);
        float h3 = __half2float(h2[(size_t)s3 * 40 + c]);
        float e0 = as2[s0] + ad, e1 = as2[s1] + ad;
        float e2 = as2[s2] + ad, e3 = as2[s3] + ad;
        e0 = e0 > 0.f ? e0 : 0.2f * e0;
        e1 = e1 > 0.f ? e1 : 0.2f * e1;
        e2 = e2 > 0.f ? e2 : 0.2f * e2;
        e3 = e3 > 0.f ? e3 : 0.2f * e3;
        float nm = fmaxf(fmaxf(m, fmaxf(e0, e1)), fmaxf(e2, e3));
        float r  = __expf(m - nm);
        float p0 = __expf(e0 - nm), p1 = __expf(e1 - nm);
        float p2 = __expf(e2 - nm), p3 = __expf(e3 - nm);
        s = s * r + (p0 + p1) + (p2 + p3);
        acc = acc * r + (p0 * h0 + p1 * h1v) + (p2 * h2v + p3 * h3);
        m = nm;
    }
    for (; i < end; ++i) {
        int s0 = colx[i];
        float hv = __half2float(h2[(size_t)s0 * 40 + c]);
        float e = as2[s0] + ad;
        e = e > 0.f ? e : 0.2f * e;
        float nm = fmaxf(m, e);
        float r = __expf(m - nm);
        float p = __expf(e - nm);
        s = s * r + p;
        acc = acc * r + p * hv;
        m = nm;
    }
    if (lane < 40) out[(size_t)n * 40 + lane] = acc / (s + 1e-16f) + b2[lane];
}

// ---------------- launch ----------------

static inline size_t rup(size_t x) { return (x + 255) & ~(size_t)255; }

extern "C" void kernel_launch(void* const* d_in, const int* in_sizes, int n_in,
                              void* d_out, int out_size, void* d_ws, size_t ws_size,
                              hipStream_t stream) {
    const float* x     = (const float*)d_in[0];
    const int*   ei    = (const int*)d_in[1];
    const float* W1    = (const float*)d_in[2];
    const float* atts1 = (const float*)d_in[3];
    const float* attd1 = (const float*)d_in[4];
    const float* b1    = (const float*)d_in[5];
    const float* gamma = (const float*)d_in[6];
    const float* beta  = (const float*)d_in[7];
    const float* W2    = (const float*)d_in[8];
    const float* atts2 = (const float*)d_in[9];
    const float* attd2 = (const float*)d_in[10];
    const float* b2    = (const float*)d_in[11];

    const int N = in_sizes[0] / 256;
    const int E = in_sizes[1] / 2;
    const int* srcv = ei;
    const int* dstv = ei + E;

    char* w = (char*)d_ws;
    __half* h1 = (__half*)w;    w += rup((size_t)N * 256 * 2);
    float* hb = (float*)w;      w += rup((size_t)N * 256 * 4);
    __half* h2 = (__half*)w;    w += rup((size_t)N * 40 * 2);
    float* as1 = (float*)w;     w += rup((size_t)N * 8 * 4);
    float* ad1 = (float*)w;     w += rup((size_t)N * 8 * 4);
    float* as2 = (float*)w;     w += rup((size_t)N * 4);
    float* ad2 = (float*)w;     w += rup((size_t)N * 4);
    int* rowptr = (int*)w;      w += rup((size_t)(N + 1) * 4);
    int* cursor = (int*)w;      w += rup((size_t)N * 4);
    int* colx = (int*)w;        w += rup((size_t)(E + N) * 4);
    int* partial = (int*)w;     w += rup(256 * 4);
    int* partoff = (int*)w;     w += rup(256 * 4);
    float* bn = (float*)w;      w += rup(1024 * 4);
    float* bnsum = bn, *bnssum = bn + 256, *scale = bn + 512, *shift = bn + 768;
    short* W1h = (short*)w;     w += rup(256 * 256 * 2);
    short* W1l = (short*)w;     w += rup(256 * 256 * 2);
    short* W2h = (short*)w;     w += rup(64 * 256 * 2);
    short* W2l = (short*)w;     w += rup(64 * 256 * 2);

    const int NB = (N + 255) / 256;   // <= 256 for N <= 65536

    // weight pre-pack (bit-identical bf16 hi/lo, transposed to [col][k])
    k_packW1<<<32, 256, 0, stream>>>(W1, W1h, W1l);
    k_packW2<<<8, 256, 0, stream>>>(W2, W2h, W2l);

    // CSR build
    hipMemsetAsync(cursor, 0, (size_t)N * 4, stream);
    hipMemsetAsync(bn, 0, 512 * 4, stream);
    k_count<<<(E + THREADS - 1) / THREADS, THREADS, 0, stream>>>(dstv, E, cursor);
    k_scanA<<<NB, 256, 0, stream>>>(cursor, partial, N);
    k_scanB<<<1, 256, 0, stream>>>(partial, partoff, rowptr, NB, N);
    k_scanC<<<NB, 256, 0, stream>>>(cursor, partoff, rowptr, colx, N);
    k_scatter<<<(E + THREADS - 1) / THREADS, THREADS, 0, stream>>>(srcv, dstv, E, cursor, colx);

    // Layer 1
    k_gemm1<<<(N + 63) / 64, 512, 0, stream>>>(x, W1h, W1l, atts1, attd1, h1, as1, ad1, N);
    k_agg1<<<(N + 3) / 4, 256, 0, stream>>>(h1, as1, ad1, rowptr, colx, b1, hb, N);

    // BatchNorm stats (ELU+apply fused into gemm2)
    k_bnstats<<<512, 256, 0, stream>>>(hb, bnsum, bnssum, N);
    k_bnfinal<<<1, 256, 0, stream>>>(bnsum, bnssum, gamma, beta, scale, shift, N);

    // Layer 2
    k_gemm2<<<(N + 63) / 64, 256, 0, stream>>>(hb, W2h, W2l, scale, shift, h2, N);
    k_alpha2<<<(N + THREADS - 1) / THREADS, THREADS, 0, stream>>>(h2, atts2, attd2, as2, ad2, N);
    k_agg2<<<(N + 3) / 4, 256, 0, stream>>>(h2, as2, ad2, rowptr, colx, b2, (float*)d_out, N);
}

// Round 15
// 408.987 us; speedup vs baseline: 2.0099x; 1.0053x over previous
//
#include <hip/hip_runtime.h>
#include <hip/hip_bf16.h>
#include <hip/hip_fp16.h>

#define THREADS 256
#define LOG2E 1.44269504f

typedef __attribute__((ext_vector_type(8))) short short8;
typedef __attribute__((ext_vector_type(4))) float f32x4;

__device__ inline unsigned short f2bf_rn(float f) {
    unsigned u = __float_as_uint(f);
    unsigned r = (u + 0x7FFF + ((u >> 16) & 1)) >> 16;
    return (unsigned short)r;
}
__device__ inline float bf2f(unsigned short s) {
    return __uint_as_float(((unsigned)s) << 16);
}
__device__ inline void bfsplit(float f, short* hi, short* lo) {
    unsigned short h = f2bf_rn(f);
    *hi = (short)h;
    *lo = (short)f2bf_rn(f - bf2f(h));
}

// ---------------- CSR build ----------------

__global__ void k_count(const int* __restrict__ dstv, int E, int* __restrict__ deg) {
    int e = blockIdx.x * THREADS + threadIdx.x;
    if (e < E) atomicAdd(&deg[dstv[e]], 1);
}

__global__ void k_scanA(const int* __restrict__ deg, int* __restrict__ partial, int Nn) {
    __shared__ int sm[256];
    int i = blockIdx.x * 256 + threadIdx.x;
    sm[threadIdx.x] = (i < Nn) ? deg[i] + 1 : 0;
    __syncthreads();
    for (int off = 128; off > 0; off >>= 1) {
        if (threadIdx.x < off) sm[threadIdx.x] += sm[threadIdx.x + off];
        __syncthreads();
    }
    if (threadIdx.x == 0) partial[blockIdx.x] = sm[0];
}

__global__ void k_scanB(const int* __restrict__ partial, int* __restrict__ partoff,
                        int* __restrict__ rowptr, int nb, int Nn) {
    __shared__ int sm[256];
    int t = threadIdx.x;
    int v = (t < nb) ? partial[t] : 0;
    sm[t] = v;
    __syncthreads();
    for (int off = 1; off < 256; off <<= 1) {
        int u = (t >= off) ? sm[t - off] : 0;
        __syncthreads();
        sm[t] += u;
        __syncthreads();
    }
    if (t < nb) partoff[t] = sm[t] - v;
    if (t == 255) rowptr[Nn] = sm[255];
}

__global__ void k_scanC(int* __restrict__ deg_cursor, const int* __restrict__ partoff,
                        int* __restrict__ rowptr, int* __restrict__ colx, int Nn) {
    __shared__ int sm[256];
    int t = threadIdx.x;
    int i = blockIdx.x * 256 + t;
    int d = (i < Nn) ? deg_cursor[i] : 0;
    int v = (i < Nn) ? d + 1 : 0;
    sm[t] = v;
    __syncthreads();
    for (int off = 1; off < 256; off <<= 1) {
        int u = (t >= off) ? sm[t - off] : 0;
        __syncthreads();
        sm[t] += u;
        __syncthreads();
    }
    int excl = sm[t] - v + partoff[blockIdx.x];
    if (i < Nn) {
        rowptr[i] = excl;
        colx[excl] = i;             // self loop first in segment
        deg_cursor[i] = excl + 1;   // scatter cursor
    }
}

__global__ void k_scatter(const int* __restrict__ srcv, const int* __restrict__ dstv,
                          int E, int* __restrict__ cursor, int* __restrict__ colx) {
    int e = blockIdx.x * THREADS + threadIdx.x;
    if (e >= E) return;
    int pos = atomicAdd(&cursor[dstv[e]], 1);
    colx[pos] = srcv[e];
}

// ---------------- weight pre-pack: W[k][col] fp32 -> Wh/Wl[col][k] bf16 ----------------

__global__ void k_packW1(const float* __restrict__ W, short* __restrict__ Wh,
                         short* __restrict__ Wl) {
    int g = blockIdx.x * 256 + threadIdx.x;   // 0..8191
    int col = g >> 5, k8 = (g & 31) * 8;
    short8 h, l;
    #pragma unroll
    for (int i = 0; i < 8; ++i) {
        short hh, ll;
        bfsplit(W[(size_t)(k8 + i) * 256 + col], &hh, &ll);
        h[i] = hh; l[i] = ll;
    }
    *(short8*)&Wh[col * 256 + k8] = h;
    *(short8*)&Wl[col * 256 + k8] = l;
}

__global__ void k_packW2(const float* __restrict__ W, short* __restrict__ Wh,
                         short* __restrict__ Wl) {
    int g = blockIdx.x * 256 + threadIdx.x;   // 0..2047
    int col = g >> 5, k8 = (g & 31) * 8;
    short8 h, l;
    #pragma unroll
    for (int i = 0; i < 8; ++i) {
        short hh = 0, ll = 0;
        if (col < 40) bfsplit(W[(size_t)(k8 + i) * 40 + col], &hh, &ll);
        h[i] = hh; l[i] = ll;
    }
    *(short8*)&Wh[col * 256 + k8] = h;
    *(short8*)&Wl[col * 256 + k8] = l;
}

// ---------------- GEMM1: A bf16-hi only, B hi/lo; fused alpha1 (scaled by log2e) ----
// h1[M,256] = x[M,256] @ W1. Block 64 rows, 512 threads = 8 waves; wave = head.

__global__ __launch_bounds__(512) void k_gemm1(const float* __restrict__ A,
                                               const short* __restrict__ W1h,
                                               const short* __restrict__ W1l,
                                               const float* __restrict__ attS,
                                               const float* __restrict__ attD,
                                               __half* __restrict__ C,
                                               float* __restrict__ as1,
                                               float* __restrict__ ad1, int M) {
    __shared__ short Ash[64][40];
    int t = threadIdx.x;
    int l = t & 63, wc = t >> 6;         // 8 waves, wave = head
    int row0 = blockIdx.x * 64;
    int l16 = l & 15, lg = l >> 4;

    f32x4 zero = {0.f, 0.f, 0.f, 0.f};
    f32x4 acc[4][2];
    #pragma unroll
    for (int i = 0; i < 4; ++i) { acc[i][0] = zero; acc[i][1] = zero; }

    for (int k0 = 0; k0 < 256; k0 += 32) {
        // stage A: 64x32 fp32 -> bf16 (512 float4 slots / 512 thr)
        {
            int r = t >> 3, c4 = t & 7;
            int grow = row0 + r;
            float4 v = {0.f, 0.f, 0.f, 0.f};
            if (grow < M) v = *(const float4*)&A[(size_t)grow * 256 + k0 + c4 * 4];
            Ash[r][c4 * 4 + 0] = (short)f2bf_rn(v.x);
            Ash[r][c4 * 4 + 1] = (short)f2bf_rn(v.y);
            Ash[r][c4 * 4 + 2] = (short)f2bf_rn(v.z);
            Ash[r][c4 * 4 + 3] = (short)f2bf_rn(v.w);
        }
        short8 bh[2], bl[2];
        #pragma unroll
        for (int nf = 0; nf < 2; ++nf) {
            int col = wc * 32 + nf * 16 + l16;
            bh[nf] = *(const short8*)&W1h[col * 256 + k0 + lg * 8];
            bl[nf] = *(const short8*)&W1l[col * 256 + k0 + lg * 8];
        }
        __syncthreads();
        #pragma unroll
        for (int mf = 0; mf < 4; ++mf) {
            short8 ah = *(const short8*)&Ash[mf * 16 + l16][lg * 8];
            #pragma unroll
            for (int nf = 0; nf < 2; ++nf) {
                acc[mf][nf] = __builtin_amdgcn_mfma_f32_16x16x32_bf16(ah, bh[nf], acc[mf][nf], 0, 0, 0);
                acc[mf][nf] = __builtin_amdgcn_mfma_f32_16x16x32_bf16(ah, bl[nf], acc[mf][nf], 0, 0, 0);
            }
        }
        __syncthreads();
    }

    // C write (fp16)
    #pragma unroll
    for (int mf = 0; mf < 4; ++mf)
        #pragma unroll
        for (int nf = 0; nf < 2; ++nf)
            #pragma unroll
            for (int j = 0; j < 4; ++j) {
                int row = row0 + mf * 16 + 4 * lg + j;
                if (row < M)
                    C[(size_t)row * 256 + wc * 32 + nf * 16 + l16] =
                        __float2half(acc[mf][nf][j]);
            }

    // fused alpha (scaled by log2e for exp2-domain softmax)
    {
        float aS0 = attS[wc * 32 + l16],      aD0 = attD[wc * 32 + l16];
        float aS1 = attS[wc * 32 + 16 + l16], aD1 = attD[wc * 32 + 16 + l16];
        #pragma unroll
        for (int mf = 0; mf < 4; ++mf) {
            float ps[4], pd[4];
            #pragma unroll
            for (int j = 0; j < 4; ++j) {
                ps[j] = acc[mf][0][j] * aS0 + acc[mf][1][j] * aS1;
                pd[j] = acc[mf][0][j] * aD0 + acc[mf][1][j] * aD1;
            }
            #pragma unroll
            for (int msk = 1; msk < 16; msk <<= 1)
                #pragma unroll
                for (int j = 0; j < 4; ++j) {
                    ps[j] += __shfl_xor(ps[j], msk);
                    pd[j] += __shfl_xor(pd[j], msk);
                }
            if (l16 == 0) {
                #pragma unroll
                for (int j = 0; j < 4; ++j) {
                    int row = row0 + mf * 16 + 4 * lg + j;
                    if (row < M) {
                        as1[row * 8 + wc] = ps[j] * LOG2E;
                        ad1[row * 8 + wc] = pd[j] * LOG2E;
                    }
                }
            }
        }
    }
}

// ---- agg1: wave per node, fp16 gather, 4-edge unrolled, exp2-domain softmax,
//      fp16 hb output ----

__global__ __launch_bounds__(256) void k_agg1(const __half* __restrict__ h1,
                                              const float* __restrict__ as1,
                                              const float* __restrict__ ad1,
                                              const int* __restrict__ rowptr,
                                              const int* __restrict__ colx,
                                              const float* __restrict__ b1,
                                              __half* __restrict__ hb, int Nn) {
    int lane = threadIdx.x & 63, w = threadIdx.x >> 6;
    int n = blockIdx.x * 4 + w;
    if (n >= Nn) return;
    int head = lane >> 3;                  // lane covers channels [4*lane, 4*lane+4)
    float ad = ad1[n * 8 + head];
    int beg = rowptr[n], end = rowptr[n + 1];
    float m = -1e30f, s = 0.f;
    float acc[4] = {};
    int i = beg;
    for (; i + 3 < end; i += 4) {
        int s0 = colx[i], s1 = colx[i + 1], s2 = colx[i + 2], s3 = colx[i + 3];
        uint2 r0 = *(const uint2*)&h1[(size_t)s0 * 256 + lane * 4];
        uint2 r1 = *(const uint2*)&h1[(size_t)s1 * 256 + lane * 4];
        uint2 r2 = *(const uint2*)&h1[(size_t)s2 * 256 + lane * 4];
        uint2 r3 = *(const uint2*)&h1[(size_t)s3 * 256 + lane * 4];
        float e0 = as1[s0 * 8 + head] + ad;
        float e1 = as1[s1 * 8 + head] + ad;
        float e2 = as1[s2 * 8 + head] + ad;
        float e3 = as1[s3 * 8 + head] + ad;
        e0 = e0 > 0.f ? e0 : 0.2f * e0;
        e1 = e1 > 0.f ? e1 : 0.2f * e1;
        e2 = e2 > 0.f ? e2 : 0.2f * e2;
        e3 = e3 > 0.f ? e3 : 0.2f * e3;
        float nm = fmaxf(fmaxf(m, fmaxf(e0, e1)), fmaxf(e2, e3));
        float r  = exp2f(m - nm);
        float p0 = exp2f(e0 - nm), p1 = exp2f(e1 - nm);
        float p2 = exp2f(e2 - nm), p3 = exp2f(e3 - nm);
        float2 f00 = __half22float2(*(__half2*)&r0.x), f01 = __half22float2(*(__half2*)&r0.y);
        float2 f10 = __half22float2(*(__half2*)&r1.x), f11 = __half22float2(*(__half2*)&r1.y);
        float2 f20 = __half22float2(*(__half2*)&r2.x), f21 = __half22float2(*(__half2*)&r2.y);
        float2 f30 = __half22float2(*(__half2*)&r3.x), f31 = __half22float2(*(__half2*)&r3.y);
        float hv0[4] = {f00.x, f00.y, f01.x, f01.y};
        float hv1[4] = {f10.x, f10.y, f11.x, f11.y};
        float hv2[4] = {f20.x, f20.y, f21.x, f21.y};
        float hv3[4] = {f30.x, f30.y, f31.x, f31.y};
        s = s * r + (p0 + p1) + (p2 + p3);
        #pragma unroll
        for (int q = 0; q < 4; ++q)
            acc[q] = acc[q] * r + (p0 * hv0[q] + p1 * hv1[q]) + (p2 * hv2[q] + p3 * hv3[q]);
        m = nm;
    }
    for (; i < end; ++i) {
        int s0 = colx[i];
        uint2 raw = *(const uint2*)&h1[(size_t)s0 * 256 + lane * 4];
        float e = as1[s0 * 8 + head] + ad;
        e = e > 0.f ? e : 0.2f * e;
        float nm = fmaxf(m, e);
        float r = exp2f(m - nm);
        float p = exp2f(e - nm);
        float2 f0 = __half22float2(*(__half2*)&raw.x);
        float2 f1 = __half22float2(*(__half2*)&raw.y);
        float hv[4] = {f0.x, f0.y, f1.x, f1.y};
        s = s * r + p;
        #pragma unroll
        for (int q = 0; q < 4; ++q) acc[q] = acc[q] * r + p * hv[q];
        m = nm;
    }
    float inv = 1.f / (s + 1e-16f);
    float4 bv = *(const float4*)&b1[lane * 4];
    __half2 o01 = __floats2half2_rn(acc[0] * inv + bv.x, acc[1] * inv + bv.y);
    __half2 o23 = __floats2half2_rn(acc[2] * inv + bv.z, acc[3] * inv + bv.w);
    uint2 ow;
    ow.x = *(unsigned*)&o01;
    ow.y = *(unsigned*)&o23;
    *(uint2*)&hb[(size_t)n * 256 + lane * 4] = ow;
}

// ---------------- BatchNorm stats (fp16 hb) ----------------

__global__ __launch_bounds__(256) void k_bnstats(const __half* __restrict__ hb,
                                                 float* __restrict__ bnsum,
                                                 float* __restrict__ bnssum, int Nn) {
    int c = threadIdx.x;
    float s = 0.f, ss = 0.f;
    for (int r = blockIdx.x; r < Nn; r += gridDim.x) {
        float v = __half2float(hb[(size_t)r * 256 + c]);
        s += v; ss += v * v;
    }
    atomicAdd(&bnsum[c], s);
    atomicAdd(&bnssum[c], ss);
}

__global__ void k_bnfinal(const float* __restrict__ bnsum, const float* __restrict__ bnssum,
                          const float* __restrict__ gamma, const float* __restrict__ beta,
                          float* __restrict__ scale, float* __restrict__ shift, int Nn) {
    int c = threadIdx.x;
    float mu = bnsum[c] / (float)Nn;
    float var = bnssum[c] / (float)Nn - mu * mu;
    float inv = rsqrtf(var + 1e-5f);
    float sc = gamma[c] * inv;
    scale[c] = sc;
    shift[c] = beta[c] - mu * sc;
}

// ---------------- GEMM2: fp16 A in, A bf16-hi only, fused BN+ELU ----------------
// h2[M,40] = elu(bn(hb)) @ W2. Block 64 rows, 256 threads = 4 waves.

__global__ __launch_bounds__(256) void k_gemm2(const __half* __restrict__ H,
                                               const short* __restrict__ W2h,
                                               const short* __restrict__ W2l,
                                               const float* __restrict__ scale,
                                               const float* __restrict__ shift,
                                               __half* __restrict__ h2, int M) {
    __shared__ short Ash[64][40];
    __shared__ float ssc[256], ssh[256];
    int t = threadIdx.x;
    ssc[t] = scale[t];
    ssh[t] = shift[t];
    int l = t & 63, wc = t >> 6;         // 4 waves
    int row0 = blockIdx.x * 64;
    int l16 = l & 15, lg = l >> 4;

    f32x4 zero = {0.f, 0.f, 0.f, 0.f};
    f32x4 acc[4];
    #pragma unroll
    for (int i = 0; i < 4; ++i) acc[i] = zero;
    __syncthreads();

    for (int k0 = 0; k0 < 256; k0 += 32) {
        #pragma unroll
        for (int p = 0; p < 2; ++p) {
            int s = t + p * 256;          // 0..511
            int r = s >> 3, c4 = s & 7;
            int grow = row0 + r;
            uint2 raw = {0u, 0u};
            if (grow < M) raw = *(const uint2*)&H[(size_t)grow * 256 + k0 + c4 * 4];
            float2 f0 = __half22float2(*(__half2*)&raw.x);
            float2 f1 = __half22float2(*(__half2*)&raw.y);
            int c = k0 + c4 * 4;
            float e0 = f0.x * ssc[c + 0] + ssh[c + 0];
            float e1 = f0.y * ssc[c + 1] + ssh[c + 1];
            float e2 = f1.x * ssc[c + 2] + ssh[c + 2];
            float e3 = f1.y * ssc[c + 3] + ssh[c + 3];
            e0 = e0 > 0.f ? e0 : __expf(e0) - 1.f;
            e1 = e1 > 0.f ? e1 : __expf(e1) - 1.f;
            e2 = e2 > 0.f ? e2 : __expf(e2) - 1.f;
            e3 = e3 > 0.f ? e3 : __expf(e3) - 1.f;
            Ash[r][c4 * 4 + 0] = (short)f2bf_rn(e0);
            Ash[r][c4 * 4 + 1] = (short)f2bf_rn(e1);
            Ash[r][c4 * 4 + 2] = (short)f2bf_rn(e2);
            Ash[r][c4 * 4 + 3] = (short)f2bf_rn(e3);
        }
        short8 bh, bl;
        {
            int col = wc * 16 + l16;      // 0..63
            bh = *(const short8*)&W2h[col * 256 + k0 + lg * 8];
            bl = *(const short8*)&W2l[col * 256 + k0 + lg * 8];
        }
        __syncthreads();
        #pragma unroll
        for (int mf = 0; mf < 4; ++mf) {
            short8 ah = *(const short8*)&Ash[mf * 16 + l16][lg * 8];
            acc[mf] = __builtin_amdgcn_mfma_f32_16x16x32_bf16(ah, bh, acc[mf], 0, 0, 0);
            acc[mf] = __builtin_amdgcn_mfma_f32_16x16x32_bf16(ah, bl, acc[mf], 0, 0, 0);
        }
        __syncthreads();
    }

    int col = wc * 16 + l16;
    #pragma unroll
    for (int mf = 0; mf < 4; ++mf)
        #pragma unroll
        for (int j = 0; j < 4; ++j) {
            int row = row0 + mf * 16 + 4 * lg + j;
            if (row < M && col < 40)
                h2[(size_t)row * 40 + col] = __float2half(acc[mf][j]);
        }
}

// ---------------- alpha2 (fp16 h2, scaled by log2e) ----------------

__global__ void k_alpha2(const __half* __restrict__ h2, const float* __restrict__ atts,
                         const float* __restrict__ attd, float* __restrict__ as2,
                         float* __restrict__ ad2, int Nn) {
    int n = blockIdx.x * THREADS + threadIdx.x;
    if (n >= Nn) return;
    const __half2* hp = (const __half2*)&h2[(size_t)n * 40];
    float s = 0.f, d = 0.f;
    #pragma unroll
    for (int j = 0; j < 20; ++j) {
        float2 v = __half22float2(hp[j]);
        s += v.x * atts[2 * j] + v.y * atts[2 * j + 1];
        d += v.x * attd[2 * j] + v.y * attd[2 * j + 1];
    }
    as2[n] = s * LOG2E;
    ad2[n] = d * LOG2E;
}

// ---- agg2: wave per node, fp16 gather, 4-edge unrolled, exp2-domain, C=40 ----

__global__ __launch_bounds__(256) void k_agg2(const __half* __restrict__ h2,
                                              const float* __restrict__ as2,
                                              const float* __restrict__ ad2,
                                              const int* __restrict__ rowptr,
                                              const int* __restrict__ colx,
                                              const float* __restrict__ b2,
                                              float* __restrict__ out, int Nn) {
    int lane = threadIdx.x & 63, w = threadIdx.x >> 6;
    int n = blockIdx.x * 4 + w;
    if (n >= Nn) return;
    float ad = ad2[n];
    int beg = rowptr[n], end = rowptr[n + 1];
    int c = lane < 40 ? lane : 0;
    float m = -1e30f, s = 0.f, acc = 0.f;
    int i = beg;
    for (; i + 3 < end; i += 4) {
        int s0 = colx[i], s1 = colx[i + 1], s2 = colx[i + 2], s3 = colx[i + 3];
        float h0 = __half2float(h2[(size_t)s0 * 40 + c]);
        float h1v = __half2float(h2[(size_t)s1 * 40 + c]);
        float h2v = __half2float(h2[(size_t)s2 * 40 + c]);
        float h3 = __half2float(h2[(size_t)s3 * 40 + c]);
        float e0 = as2[s0] + ad, e1 = as2[s1] + ad;
        float e2 = as2[s2] + ad, e3 = as2[s3] + ad;
        e0 = e0 > 0.f ? e0 : 0.2f * e0;
        e1 = e1 > 0.f ? e1 : 0.2f * e1;
        e2 = e2 > 0.f ? e2 : 0.2f * e2;
        e3 = e3 > 0.f ? e3 : 0.2f * e3;
        float nm = fmaxf(fmaxf(m, fmaxf(e0, e1)), fmaxf(e2, e3));
        float r  = exp2f(m - nm);
        float p0 = exp2f(e0 - nm), p1 = exp2f(e1 - nm);
        float p2 = exp2f(e2 - nm), p3 = exp2f(e3 - nm);
        s = s * r + (p0 + p1) + (p2 + p3);
        acc = acc * r + (p0 * h0 + p1 * h1v) + (p2 * h2v + p3 * h3);
        m = nm;
    }
    for (; i < end; ++i) {
        int s0 = colx[i];
        float hv = __half2float(h2[(size_t)s0 * 40 + c]);
        float e = as2[s0] + ad;
        e = e > 0.f ? e : 0.2f * e;
        float nm = fmaxf(m, e);
        float r = exp2f(m - nm);
        float p = exp2f(e - nm);
        s = s * r + p;
        acc = acc * r + p * hv;
        m = nm;
    }
    if (lane < 40) out[(size_t)n * 40 + lane] = acc / (s + 1e-16f) + b2[lane];
}

// ---------------- launch ----------------

static inline size_t rup(size_t x) { return (x + 255) & ~(size_t)255; }

extern "C" void kernel_launch(void* const* d_in, const int* in_sizes, int n_in,
                              void* d_out, int out_size, void* d_ws, size_t ws_size,
                              hipStream_t stream) {
    const float* x     = (const float*)d_in[0];
    const int*   ei    = (const int*)d_in[1];
    const float* W1    = (const float*)d_in[2];
    const float* atts1 = (const float*)d_in[3];
    const float* attd1 = (const float*)d_in[4];
    const float* b1    = (const float*)d_in[5];
    const float* gamma = (const float*)d_in[6];
    const float* beta  = (const float*)d_in[7];
    const float* W2    = (const float*)d_in[8];
    const float* atts2 = (const float*)d_in[9];
    const float* attd2 = (const float*)d_in[10];
    const float* b2    = (const float*)d_in[11];

    const int N = in_sizes[0] / 256;
    const int E = in_sizes[1] / 2;
    const int* srcv = ei;
    const int* dstv = ei + E;

    char* w = (char*)d_ws;
    __half* h1 = (__half*)w;    w += rup((size_t)N * 256 * 2);
    __half* hb = (__half*)w;    w += rup((size_t)N * 256 * 2);
    __half* h2 = (__half*)w;    w += rup((size_t)N * 40 * 2);
    float* as1 = (float*)w;     w += rup((size_t)N * 8 * 4);
    float* ad1 = (float*)w;     w += rup((size_t)N * 8 * 4);
    float* as2 = (float*)w;     w += rup((size_t)N * 4);
    float* ad2 = (float*)w;     w += rup((size_t)N * 4);
    int* rowptr = (int*)w;      w += rup((size_t)(N + 1) * 4);
    int* cursor = (int*)w;      w += rup((size_t)N * 4);
    int* colx = (int*)w;        w += rup((size_t)(E + N) * 4);
    int* partial = (int*)w;     w += rup(256 * 4);
    int* partoff = (int*)w;     w += rup(256 * 4);
    float* bn = (float*)w;      w += rup(1024 * 4);
    float* bnsum = bn, *bnssum = bn + 256, *scale = bn + 512, *shift = bn + 768;
    short* W1h = (short*)w;     w += rup(256 * 256 * 2);
    short* W1l = (short*)w;     w += rup(256 * 256 * 2);
    short* W2h = (short*)w;     w += rup(64 * 256 * 2);
    short* W2l = (short*)w;     w += rup(64 * 256 * 2);

    const int NB = (N + 255) / 256;   // <= 256 for N <= 65536

    // weight pre-pack (bf16 hi/lo, transposed to [col][k])
    k_packW1<<<32, 256, 0, stream>>>(W1, W1h, W1l);
    k_packW2<<<8, 256, 0, stream>>>(W2, W2h, W2l);

    // CSR build
    hipMemsetAsync(cursor, 0, (size_t)N * 4, stream);
    hipMemsetAsync(bn, 0, 512 * 4, stream);
    k_count<<<(E + THREADS - 1) / THREADS, THREADS, 0, stream>>>(dstv, E, cursor);
    k_scanA<<<NB, 256, 0, stream>>>(cursor, partial, N);
    k_scanB<<<1, 256, 0, stream>>>(partial, partoff, rowptr, NB, N);
    k_scanC<<<NB, 256, 0, stream>>>(cursor, partoff, rowptr, colx, N);
    k_scatter<<<(E + THREADS - 1) / THREADS, THREADS, 0, stream>>>(srcv, dstv, E, cursor, colx);

    // Layer 1
    k_gemm1<<<(N + 63) / 64, 512, 0, stream>>>(x, W1h, W1l, atts1, attd1, h1, as1, ad1, N);
    k_agg1<<<(N + 3) / 4, 256, 0, stream>>>(h1, as1, ad1, rowptr, colx, b1, hb, N);

    // BatchNorm stats (ELU+apply fused into gemm2)
    k_bnstats<<<512, 256, 0, stream>>>(hb, bnsum, bnssum, N);
    k_bnfinal<<<1, 256, 0, stream>>>(bnsum, bnssum, gamma, beta, scale, shift, N);

    // Layer 2
    k_gemm2<<<(N + 63) / 64, 256, 0, stream>>>(hb, W2h, W2l, scale, shift, h2, N);
    k_alpha2<<<(N + THREADS - 1) / THREADS, THREADS, 0, stream>>>(h2, atts2, attd2, as2, ad2, N);
    k_agg2<<<(N + 3) / 4, 256, 0, stream>>>(h2, as2, ad2, rowptr, colx, b2, (float*)d_out, N);
}